// Round 1
// baseline (795.189 us; speedup 1.0000x reference)
//
#include <hip/hip_runtime.h>

#define LSEQ   2048
#define NBATCH 2
#define DMODEL 512
#define DINNER 1024
#define NSTATE 16
#define MROWS  4096   // NBATCH*LSEQ

// ---------- fast math helpers ----------
__device__ __forceinline__ float fast_exp2(float x){
#if __has_builtin(__builtin_amdgcn_exp2f)
    return __builtin_amdgcn_exp2f(x);
#else
    return exp2f(x);
#endif
}
__device__ __forceinline__ float fast_log2(float x){
#if __has_builtin(__builtin_amdgcn_logf)
    return __builtin_amdgcn_logf(x);
#else
    return log2f(x);
#endif
}
__device__ __forceinline__ float fast_rcp(float x){
#if __has_builtin(__builtin_amdgcn_rcpf)
    return __builtin_amdgcn_rcpf(x);
#else
    return 1.f/x;
#endif
}
__device__ __forceinline__ float silu_f(float x){
    // x * sigmoid(x)
    float e = fast_exp2(-x * 1.4426950408889634f);
    return x * fast_rcp(1.f + e);
}
__device__ __forceinline__ float softplus_f(float x){
    if (x > 20.f) return x;
    float e = fast_exp2(x * 1.4426950408889634f);
    return 0.6931471805599453f * fast_log2(1.f + e);
}
// DPP rotate-within-row16, returns permuted src (for rotation-tree reductions on VALU pipe)
template<int CTRL>
__device__ __forceinline__ float dpp_rot(float x){
    int r = __builtin_amdgcn_update_dpp(0, __builtin_bit_cast(int, x), CTRL, 0xF, 0xF, true);
    return __builtin_bit_cast(float, r);
}

// ---------- LayerNorm (one row of 512 per block; optional residual) ----------
__global__ __launch_bounds__(256) void ln_kernel(
    const float* __restrict__ in, const float* __restrict__ res,
    const float* __restrict__ w, const float* __restrict__ bsc,
    float* __restrict__ out)
{
    int row = blockIdx.x;
    int tid = threadIdx.x;
    size_t base = (size_t)row * DMODEL;
    float v0 = in[base + tid], v1 = in[base + tid + 256];
    if (res){ v0 += res[base + tid]; v1 += res[base + tid + 256]; }
    float s = v0 + v1, s2 = v0*v0 + v1*v1;
    #pragma unroll
    for (int off = 32; off > 0; off >>= 1){
        s  += __shfl_down(s,  off, 64);
        s2 += __shfl_down(s2, off, 64);
    }
    __shared__ float red[8];
    int wid = tid >> 6;
    if ((tid & 63) == 0){ red[wid] = s; red[4 + wid] = s2; }
    __syncthreads();
    if (tid == 0){
        float a = red[0] + red[1] + red[2] + red[3];
        float c = red[4] + red[5] + red[6] + red[7];
        float m = a * (1.f / DMODEL);
        red[0] = m;
        red[1] = c * (1.f / DMODEL) - m * m;
    }
    __syncthreads();
    float mean = red[0];
    float rs = rsqrtf(red[1] + 1e-5f);
    out[base + tid]       = (v0 - mean) * rs * w[tid]       + bsc[tid];
    out[base + tid + 256] = (v1 - mean) * rs * w[tid + 256] + bsc[tid + 256];
}

// ---------- Generic B^T GEMM: C[M,N] = A[M,K] (+A2) @ W[N,K]^T, fp32 tiled ----------
// EPI: 0 = plain store, 1 = softplus(x + bias[n])
template<int BM,int BN,int BK,int TM,int TN,int EPI>
__global__ __launch_bounds__(256) void gemm_bt(
    const float* __restrict__ A, const float* __restrict__ A2,
    const float* __restrict__ W, const float* __restrict__ bias,
    float* __restrict__ C, int K, int lda, int ldw, int ldc)
{
    constexpr int NTX = BN / TN;
    constexpr int NTY = BM / TM;
    static_assert(NTX * NTY == 256, "thread map");
    static_assert(BK % 4 == 0 && TM % 4 == 0 && TN % 4 == 0, "vec4");
    __shared__ float As[BK][BM + 4];
    __shared__ float Ws[BK][BN + 4];
    int tid = threadIdx.x;
    int tx = tid % NTX, ty = tid / NTX;
    int m0 = blockIdx.y * BM, n0 = blockIdx.x * BN;
    float acc[TM][TN] = {};
    for (int k0 = 0; k0 < K; k0 += BK){
        for (int idx = tid * 4; idx < BM * BK; idx += 1024){
            int r = idx / BK, cc = idx % BK;
            const float* ga = A + (size_t)(m0 + r) * lda + k0 + cc;
            float4 v = *reinterpret_cast<const float4*>(ga);
            if (A2){
                const float* g2 = A2 + (size_t)(m0 + r) * lda + k0 + cc;
                float4 v2 = *reinterpret_cast<const float4*>(g2);
                v.x += v2.x; v.y += v2.y; v.z += v2.z; v.w += v2.w;
            }
            As[cc + 0][r] = v.x; As[cc + 1][r] = v.y;
            As[cc + 2][r] = v.z; As[cc + 3][r] = v.w;
        }
        for (int idx = tid * 4; idx < BN * BK; idx += 1024){
            int r = idx / BK, cc = idx % BK;
            const float* gw = W + (size_t)(n0 + r) * ldw + k0 + cc;
            float4 v = *reinterpret_cast<const float4*>(gw);
            Ws[cc + 0][r] = v.x; Ws[cc + 1][r] = v.y;
            Ws[cc + 2][r] = v.z; Ws[cc + 3][r] = v.w;
        }
        __syncthreads();
        #pragma unroll
        for (int kk = 0; kk < BK; kk++){
            float a[TM], bb[TN];
            #pragma unroll
            for (int i = 0; i < TM; i += 4){
                float4 t4 = *reinterpret_cast<const float4*>(&As[kk][ty * TM + i]);
                a[i] = t4.x; a[i+1] = t4.y; a[i+2] = t4.z; a[i+3] = t4.w;
            }
            #pragma unroll
            for (int j = 0; j < TN; j += 4){
                float4 t4 = *reinterpret_cast<const float4*>(&Ws[kk][tx * TN + j]);
                bb[j] = t4.x; bb[j+1] = t4.y; bb[j+2] = t4.z; bb[j+3] = t4.w;
            }
            #pragma unroll
            for (int i = 0; i < TM; i++)
                #pragma unroll
                for (int j = 0; j < TN; j++)
                    acc[i][j] = fmaf(a[i], bb[j], acc[i][j]);
        }
        __syncthreads();
    }
    #pragma unroll
    for (int i = 0; i < TM; i++){
        int m = m0 + ty * TM + i;
        #pragma unroll
        for (int j = 0; j < TN; j += 4){
            int nn = n0 + tx * TN + j;
            float4 v;
            v.x = acc[i][j]; v.y = acc[i][j+1]; v.z = acc[i][j+2]; v.w = acc[i][j+3];
            if (EPI == 1){
                v.x = softplus_f(v.x + bias[nn]);
                v.y = softplus_f(v.y + bias[nn+1]);
                v.z = softplus_f(v.z + bias[nn+2]);
                v.w = softplus_f(v.w + bias[nn+3]);
            }
            *reinterpret_cast<float4*>(C + (size_t)m * ldc + nn) = v;
        }
    }
}

// ---------- depthwise causal conv(K=4) + SiLU; dir=1 reads u reversed, outputs in reversed order ----------
__global__ __launch_bounds__(256) void conv_silu_kernel(
    const float* __restrict__ uxb,
    const float* __restrict__ w_f, const float* __restrict__ b_f,
    const float* __restrict__ w_b, const float* __restrict__ b_b,
    float* __restrict__ uc_f, float* __restrict__ uc_b)
{
    const int dir = blockIdx.y;
    const float* __restrict__ w    = dir ? w_b : w_f;
    const float* __restrict__ bias = dir ? b_b : b_f;
    float* __restrict__ uc         = dir ? uc_b : uc_f;
    int idx = blockIdx.x * 256 + threadIdx.x;       // float4 index
    int e = idx * 4;
    int dq = e & (DINNER - 1);
    int t  = (e / DINNER) & (LSEQ - 1);
    int b  = e / (DINNER * LSEQ);
    float wk[16];
    const float* wp = w + dq * 4;                   // conv_w[(d)(1)(k)] -> w[d*4+k]
    #pragma unroll
    for (int i = 0; i < 16; i++) wk[i] = wp[i];
    float4 acc = { bias[dq], bias[dq+1], bias[dq+2], bias[dq+3] };
    #pragma unroll
    for (int k = 0; k < 4; k++){
        int src = t + k - 3;
        if (src >= 0){
            int gt = dir ? (LSEQ - 1 - src) : src;
            float4 uv = *reinterpret_cast<const float4*>(uxb + ((size_t)b * LSEQ + gt) * 2048 + dq);
            acc.x = fmaf(wk[k],      uv.x, acc.x);
            acc.y = fmaf(wk[4 + k],  uv.y, acc.y);
            acc.z = fmaf(wk[8 + k],  uv.z, acc.z);
            acc.w = fmaf(wk[12 + k], uv.w, acc.w);
        }
    }
    acc.x = silu_f(acc.x); acc.y = silu_f(acc.y);
    acc.z = silu_f(acc.z); acc.w = silu_f(acc.w);
    *reinterpret_cast<float4*>(uc + ((size_t)b * LSEQ + t) * DINNER + dq) = acc;
}

// ---------- g = silu(z), z = ux[:, 1024:2048] ----------
__global__ __launch_bounds__(256) void g_kernel(const float* __restrict__ uxb, float* __restrict__ g)
{
    int i = blockIdx.x * 256 + threadIdx.x;         // over MROWS*DINNER/4
    int m = i >> 8;
    int dq = (i & 255) << 2;
    float4 z = *reinterpret_cast<const float4*>(uxb + (size_t)m * 2048 + 1024 + dq);
    z.x = silu_f(z.x); z.y = silu_f(z.y); z.z = silu_f(z.z); z.w = silu_f(z.w);
    *reinterpret_cast<float4*>(g + (size_t)m * DINNER + dq) = z;
}

// ---------- selective scan: blocks 0..127 fw, 128..255 bw; 16 channels/block, 16 states/channel ----------
__global__ __launch_bounds__(256) void scan_kernel(
    const float* __restrict__ delta_f, const float* __restrict__ delta_b,
    const float* __restrict__ uc_f,    const float* __restrict__ uc_b,
    const float* __restrict__ xdbl_f,  const float* __restrict__ xdbl_b,
    const float* __restrict__ gbuf,
    const float* __restrict__ Alog_f,  const float* __restrict__ Alog_b,
    const float* __restrict__ Dv_f,    const float* __restrict__ Dv_b,
    float* __restrict__ ybuf_f, float* __restrict__ ybuf_b)
{
    constexpr int TC = 64, P = 68;   // P: pad pitch for bank spread + 16B alignment
    __shared__ float sDel[16 * P], sDU[16 * P], sB[16 * P], sC[16 * P], sY[16 * P];
    const int tid = threadIdx.x;
    const int dir = blockIdx.x >> 7;
    const int blk = blockIdx.x & 127;
    const int cl = tid >> 4;         // channel within block (compute role)
    const int n  = tid & 15;         // state index
    const int ch0 = blk << 4;
    const int b  = ch0 >> 10;
    const int d0 = ch0 & 1023;
    const float* __restrict__ delta = dir ? delta_b : delta_f;
    const float* __restrict__ uc    = dir ? uc_b    : uc_f;
    const float* __restrict__ xdbl  = dir ? xdbl_b  : xdbl_f;
    const float* __restrict__ Alog  = dir ? Alog_b  : Alog_f;
    const float* __restrict__ Dv    = dir ? Dv_b    : Dv_f;
    float* __restrict__ ybuf        = dir ? ybuf_b  : ybuf_f;

    const float L2E = 1.4426950408889634f;
    // A = -exp(A_log); pre-fold log2(e) so the inner loop uses raw v_exp_f32 (exp2)
    const float A2 = -fast_exp2(Alog[(d0 + cl) * NSTATE + n] * L2E) * L2E;
    float h = 0.f;
    const int sc = tid & 15;         // channel (staging/write role)
    const int st = tid >> 4;         // t sub-index 0..15
    const size_t rb = (size_t)b * LSEQ;

    for (int t0 = 0; t0 < LSEQ; t0 += TC){
        // ---- stage chunk into LDS ([channel][t] major, b128-readable along t) ----
        #pragma unroll
        for (int tt = 0; tt < TC; tt += 16){
            int t = st + tt;
            size_t m = rb + t0 + t;
            float dl = delta[m * DINNER + d0 + sc];
            float uv = uc[m * DINNER + d0 + sc];
            sDel[sc * P + t] = dl;
            sDU [sc * P + t] = dl * uv;
            sB  [sc * P + t] = xdbl[m * 64 + 32 + sc];
            sC  [sc * P + t] = xdbl[m * 64 + 48 + sc];
        }
        __syncthreads();
        // ---- recurrence ----
        const float* pD = sDel + cl * P;
        const float* pU = sDU  + cl * P;
        const float* pB = sB   + n  * P;
        const float* pC = sC   + n  * P;
        for (int tq = 0; tq < TC; tq += 4){
            float4 dv  = *reinterpret_cast<const float4*>(pD + tq);
            float4 duv = *reinterpret_cast<const float4*>(pU + tq);
            float4 Bv  = *reinterpret_cast<const float4*>(pB + tq);
            float4 Cv  = *reinterpret_cast<const float4*>(pC + tq);
            float4 py;
            {
                float dA = fast_exp2(dv.x * A2);
                h = fmaf(dA, h, duv.x * Bv.x);
                float p = h * Cv.x;
                p += dpp_rot<0x128>(p); p += dpp_rot<0x124>(p);
                p += dpp_rot<0x122>(p); p += dpp_rot<0x121>(p);
                py.x = p;
            }
            {
                float dA = fast_exp2(dv.y * A2);
                h = fmaf(dA, h, duv.y * Bv.y);
                float p = h * Cv.y;
                p += dpp_rot<0x128>(p); p += dpp_rot<0x124>(p);
                p += dpp_rot<0x122>(p); p += dpp_rot<0x121>(p);
                py.y = p;
            }
            {
                float dA = fast_exp2(dv.z * A2);
                h = fmaf(dA, h, duv.z * Bv.z);
                float p = h * Cv.z;
                p += dpp_rot<0x128>(p); p += dpp_rot<0x124>(p);
                p += dpp_rot<0x122>(p); p += dpp_rot<0x121>(p);
                py.z = p;
            }
            {
                float dA = fast_exp2(dv.w * A2);
                h = fmaf(dA, h, duv.w * Bv.w);
                float p = h * Cv.w;
                p += dpp_rot<0x128>(p); p += dpp_rot<0x124>(p);
                p += dpp_rot<0x122>(p); p += dpp_rot<0x121>(p);
                py.w = p;
            }
            if (n == 0) *reinterpret_cast<float4*>(sY + cl * P + tq) = py;
        }
        __syncthreads();
        // ---- write y*g (bw maps back to original sequence index) ----
        #pragma unroll
        for (int tt = 0; tt < TC; tt += 16){
            int t = st + tt;
            int gt = t0 + t;
            size_t m = rb + gt;
            float y = sY[sc * P + t] + uc[m * DINNER + d0 + sc] * Dv[d0 + sc];
            int ot = dir ? (LSEQ - 1 - gt) : gt;
            size_t mo = rb + ot;
            float gv = gbuf[mo * DINNER + d0 + sc];
            ybuf[mo * DINNER + d0 + sc] = y * gv;
        }
        __syncthreads();
    }
}

// ---------- host launch ----------
extern "C" void kernel_launch(void* const* d_in, const int* in_sizes, int n_in,
                              void* d_out, int out_size, void* d_ws, size_t ws_size,
                              hipStream_t stream)
{
    const float* x         = (const float*)d_in[0];
    const float* ln1_w     = (const float*)d_in[1];
    const float* ln1_b     = (const float*)d_in[2];
    const float* ln2_w     = (const float*)d_in[3];
    const float* ln2_b     = (const float*)d_in[4];
    const float* in_proj_w = (const float*)d_in[5];
    const float* conv_w_f  = (const float*)d_in[6];
    const float* conv_b_f  = (const float*)d_in[7];
    const float* xproj_f   = (const float*)d_in[8];
    const float* dt_w_f    = (const float*)d_in[9];
    const float* dt_b_f    = (const float*)d_in[10];
    const float* Alog_f    = (const float*)d_in[11];
    const float* D_f       = (const float*)d_in[12];
    const float* conv_w_b  = (const float*)d_in[13];
    const float* conv_b_b  = (const float*)d_in[14];
    const float* xproj_b   = (const float*)d_in[15];
    const float* dt_w_b    = (const float*)d_in[16];
    const float* dt_b_b    = (const float*)d_in[17];
    const float* Alog_b    = (const float*)d_in[18];
    const float* D_b       = (const float*)d_in[19];
    const float* outproj   = (const float*)d_in[20];
    float* out = (float*)d_out;

    // workspace layout (floats). uxb region is reused for delta_{f,b} once ux is dead.
    float* ws      = (float*)d_ws;
    float* xn      = ws;                    // 2,097,152   (reused as out_pre)
    float* out_pre = ws;
    float* uxb     = ws + 2097152;          // 8,388,608   [u | z]
    float* delta_f = uxb;                   // alias (written after all ux readers)
    float* delta_b = uxb + 4194304;
    float* uc_f    = uxb + 8388608;         // 4,194,304
    float* uc_b    = uc_f + 4194304;        // 4,194,304
    float* gbuf    = uc_b + 4194304;        // 4,194,304
    float* xdbl_f  = gbuf + 4194304;        // 262,144
    float* xdbl_b  = xdbl_f + 262144;       // 262,144
    float* ybuf_f  = xdbl_b + 262144;       // 4,194,304
    float* ybuf_b  = ybuf_f + 4194304;      // 4,194,304  -> total ~122 MB

    // 1. LN1
    ln_kernel<<<MROWS, 256, 0, stream>>>(x, nullptr, ln1_w, ln1_b, xn);
    // 2. in_proj: ux[4096,2048] = xn @ in_proj_w^T
    gemm_bt<128,128,8,8,8,0><<<dim3(16,32), 256, 0, stream>>>(
        xn, nullptr, in_proj_w, nullptr, uxb, 512, 512, 512, 2048);
    // 3. causal conv + silu (fw & bw)
    conv_silu_kernel<<<dim3(4096,2), 256, 0, stream>>>(
        uxb, conv_w_f, conv_b_f, conv_w_b, conv_b_b, uc_f, uc_b);
    // 4. g = silu(z)
    g_kernel<<<4096, 256, 0, stream>>>(uxb, gbuf);
    // 5. x_proj: xdbl[4096,64] = uc @ x_proj_w^T
    gemm_bt<128,64,16,8,4,0><<<dim3(1,32), 256, 0, stream>>>(
        uc_f, nullptr, xproj_f, nullptr, xdbl_f, 1024, 1024, 1024, 64);
    gemm_bt<128,64,16,8,4,0><<<dim3(1,32), 256, 0, stream>>>(
        uc_b, nullptr, xproj_b, nullptr, xdbl_b, 1024, 1024, 1024, 64);
    // 6. delta = softplus(xdbl[:, :32] @ dt_w^T + dt_b)   (overwrites dead ux region)
    gemm_bt<128,128,8,8,8,1><<<dim3(8,32), 256, 0, stream>>>(
        xdbl_f, nullptr, dt_w_f, dt_b_f, delta_f, 32, 64, 32, 1024);
    gemm_bt<128,128,8,8,8,1><<<dim3(8,32), 256, 0, stream>>>(
        xdbl_b, nullptr, dt_w_b, dt_b_b, delta_b, 32, 64, 32, 1024);
    // 7. selective scan, fw+bw concurrent, writes (y + uc*D)*g
    scan_kernel<<<256, 256, 0, stream>>>(
        delta_f, delta_b, uc_f, uc_b, xdbl_f, xdbl_b, gbuf,
        Alog_f, Alog_b, D_f, D_b, ybuf_f, ybuf_b);
    // 8. out_proj: out_pre = (ybuf_f + ybuf_b) @ out_proj_w^T
    gemm_bt<128,128,8,8,8,0><<<dim3(4,32), 256, 0, stream>>>(
        ybuf_f, ybuf_b, outproj, nullptr, out_pre, 1024, 1024, 1024, 512);
    // 9. LN2(out + x) -> d_out
    ln_kernel<<<MROWS, 256, 0, stream>>>(out_pre, x, ln2_w, ln2_b, out);
}

// Round 2
// 416.882 us; speedup vs baseline: 1.9075x; 1.9075x over previous
//
#include <hip/hip_runtime.h>

#define LSEQ   2048
#define NBATCH 2
#define DMODEL 512
#define DINNER 1024
#define NSTATE 16
#define MROWS  4096   // NBATCH*LSEQ

typedef __bf16 bf16x8 __attribute__((ext_vector_type(8)));
typedef short  short8 __attribute__((ext_vector_type(8)));
typedef float  f32x4  __attribute__((ext_vector_type(4)));

// ---------- fast math helpers ----------
__device__ __forceinline__ float fast_exp2(float x){
#if __has_builtin(__builtin_amdgcn_exp2f)
    return __builtin_amdgcn_exp2f(x);
#else
    return exp2f(x);
#endif
}
__device__ __forceinline__ float fast_log2(float x){
#if __has_builtin(__builtin_amdgcn_logf)
    return __builtin_amdgcn_logf(x);
#else
    return log2f(x);
#endif
}
__device__ __forceinline__ float fast_rcp(float x){
#if __has_builtin(__builtin_amdgcn_rcpf)
    return __builtin_amdgcn_rcpf(x);
#else
    return 1.f/x;
#endif
}
__device__ __forceinline__ float silu_f(float x){
    float e = fast_exp2(-x * 1.4426950408889634f);
    return x * fast_rcp(1.f + e);
}
__device__ __forceinline__ float softplus_f(float x){
    if (x > 20.f) return x;
    float e = fast_exp2(x * 1.4426950408889634f);
    return 0.6931471805599453f * fast_log2(1.f + e);
}
// fp32 -> bf16 round-nearest-even (inputs are finite)
__device__ __forceinline__ unsigned short f2bf(float f){
    unsigned u = __builtin_bit_cast(unsigned, f);
    u += 0x7FFFu + ((u >> 16) & 1u);
    return (unsigned short)(u >> 16);
}
// DPP rotate-within-row16 (VALU-pipe 16-lane reduction)
template<int CTRL>
__device__ __forceinline__ float dpp_rot(float x){
    int r = __builtin_amdgcn_update_dpp(0, __builtin_bit_cast(int, x), CTRL, 0xF, 0xF, true);
    return __builtin_bit_cast(float, r);
}

// ---------- LayerNorm (one row of 512 per block; optional residual) ----------
__global__ __launch_bounds__(256) void ln_kernel(
    const float* __restrict__ in, const float* __restrict__ res,
    const float* __restrict__ w, const float* __restrict__ bsc,
    float* __restrict__ out)
{
    int row = blockIdx.x;
    int tid = threadIdx.x;
    size_t base = (size_t)row * DMODEL;
    float v0 = in[base + tid], v1 = in[base + tid + 256];
    if (res){ v0 += res[base + tid]; v1 += res[base + tid + 256]; }
    float s = v0 + v1, s2 = v0*v0 + v1*v1;
    #pragma unroll
    for (int off = 32; off > 0; off >>= 1){
        s  += __shfl_down(s,  off, 64);
        s2 += __shfl_down(s2, off, 64);
    }
    __shared__ float red[8];
    int wid = tid >> 6;
    if ((tid & 63) == 0){ red[wid] = s; red[4 + wid] = s2; }
    __syncthreads();
    if (tid == 0){
        float a = red[0] + red[1] + red[2] + red[3];
        float c = red[4] + red[5] + red[6] + red[7];
        float m = a * (1.f / DMODEL);
        red[0] = m;
        red[1] = c * (1.f / DMODEL) - m * m;
    }
    __syncthreads();
    float mean = red[0];
    float rs = rsqrtf(red[1] + 1e-5f);
    out[base + tid]       = (v0 - mean) * rs * w[tid]       + bsc[tid];
    out[base + tid + 256] = (v1 - mean) * rs * w[tid + 256] + bsc[tid + 256];
}

// ---------- bf16 MFMA GEMM body: C[M,N] = (A (+A2)) @ W^T ----------
// A fp32 [.., lda], W fp32 [N rows, ldw], C fp32 [.., ldc]; fp32->bf16 in staging.
// Fragment layouts (16x16x32 bf16, verified m89/m91/m120):
//   A-frag: A[m = lane&15][k = (lane>>4)*8 + j]
//   B-frag: B[k = (lane>>4)*8 + j][n = lane&15]   (B = W^T -> read Ws[n][k])
//   D:      D[row = (lane>>4)*4 + r][col = lane&15]
// EPI: 0 plain, 1 softplus(acc + bias[n])
template<int BM,int BN,int BK,int NWM,int NWN,int EPI>
__device__ __forceinline__ void gemm_body(
    const float* __restrict__ A, const float* __restrict__ A2,
    const float* __restrict__ W, const float* __restrict__ bias,
    float* __restrict__ C, int K, int lda, int ldw, int ldc)
{
    constexpr int BKp = BK + 8;              // bf16 pitch: +16B pad -> 80B rows, 2-way-max bank spread
    constexpr int FM  = BM / (16 * NWM);
    constexpr int FN  = BN / (16 * NWN);
    static_assert(NWM * NWN == 4, "4 waves");
    static_assert(BK % 32 == 0, "K-step");
    __shared__ unsigned short As[BM * BKp];
    __shared__ unsigned short Ws[BN * BKp];
    const int tid  = threadIdx.x;
    const int wave = tid >> 6, lane = tid & 63;
    const int row16 = lane & 15, q = lane >> 4;
    const int wm = (wave / NWN) * (FM * 16);
    const int wn = (wave % NWN) * (FN * 16);
    const int m0 = blockIdx.y * BM;
    const int n0 = blockIdx.x * BN;
    f32x4 acc[FM][FN] = {};

    for (int k0 = 0; k0 < K; k0 += BK){
        // ---- stage A (fp32 -> bf16) ----
        #pragma unroll
        for (int idx = tid * 8; idx < BM * BK; idx += 2048){
            int r = idx / BK, c = idx % BK;
            const float* g = A + (size_t)(m0 + r) * lda + k0 + c;
            float4 v0 = *(const float4*)g, v1 = *(const float4*)(g + 4);
            if (A2){
                const float* g2 = A2 + (size_t)(m0 + r) * lda + k0 + c;
                float4 w0 = *(const float4*)g2, w1 = *(const float4*)(g2 + 4);
                v0.x += w0.x; v0.y += w0.y; v0.z += w0.z; v0.w += w0.w;
                v1.x += w1.x; v1.y += w1.y; v1.z += w1.z; v1.w += w1.w;
            }
            short8 s;
            s[0] = (short)f2bf(v0.x); s[1] = (short)f2bf(v0.y);
            s[2] = (short)f2bf(v0.z); s[3] = (short)f2bf(v0.w);
            s[4] = (short)f2bf(v1.x); s[5] = (short)f2bf(v1.y);
            s[6] = (short)f2bf(v1.z); s[7] = (short)f2bf(v1.w);
            *(short8*)(As + r * BKp + c) = s;
        }
        // ---- stage W ----
        #pragma unroll
        for (int idx = tid * 8; idx < BN * BK; idx += 2048){
            int r = idx / BK, c = idx % BK;
            const float* g = W + (size_t)(n0 + r) * ldw + k0 + c;
            float4 v0 = *(const float4*)g, v1 = *(const float4*)(g + 4);
            short8 s;
            s[0] = (short)f2bf(v0.x); s[1] = (short)f2bf(v0.y);
            s[2] = (short)f2bf(v0.z); s[3] = (short)f2bf(v0.w);
            s[4] = (short)f2bf(v1.x); s[5] = (short)f2bf(v1.y);
            s[6] = (short)f2bf(v1.z); s[7] = (short)f2bf(v1.w);
            *(short8*)(Ws + r * BKp + c) = s;
        }
        __syncthreads();
        // ---- MFMA ----
        #pragma unroll
        for (int ks = 0; ks < BK; ks += 32){
            bf16x8 af[FM], bfr[FN];
            #pragma unroll
            for (int i = 0; i < FM; i++){
                const unsigned short* p = As + (wm + i * 16 + row16) * BKp + ks + q * 8;
                af[i] = __builtin_bit_cast(bf16x8, *(const short8*)p);
            }
            #pragma unroll
            for (int j = 0; j < FN; j++){
                const unsigned short* p = Ws + (wn + j * 16 + row16) * BKp + ks + q * 8;
                bfr[j] = __builtin_bit_cast(bf16x8, *(const short8*)p);
            }
            #pragma unroll
            for (int i = 0; i < FM; i++)
                #pragma unroll
                for (int j = 0; j < FN; j++)
                    acc[i][j] = __builtin_amdgcn_mfma_f32_16x16x32_bf16(af[i], bfr[j], acc[i][j], 0, 0, 0);
        }
        __syncthreads();
    }
    // ---- epilogue ----
    #pragma unroll
    for (int j = 0; j < FN; j++){
        int n = n0 + wn + j * 16 + row16;
        float bv = (EPI == 1) ? bias[n] : 0.f;
        #pragma unroll
        for (int i = 0; i < FM; i++){
            #pragma unroll
            for (int r = 0; r < 4; r++){
                int m = m0 + wm + i * 16 + q * 4 + r;
                float v = acc[i][j][r];
                if (EPI == 1) v = softplus_f(v + bv);
                C[(size_t)m * ldc + n] = v;
            }
        }
    }
}

template<int BM,int BN,int BK,int NWM,int NWN,int EPI>
__global__ __launch_bounds__(256) void gemm_mfma(
    const float* __restrict__ A, const float* __restrict__ A2,
    const float* __restrict__ W, const float* __restrict__ bias,
    float* __restrict__ C, int K, int lda, int ldw, int ldc)
{
    gemm_body<BM,BN,BK,NWM,NWN,EPI>(A, A2, W, bias, C, K, lda, ldw, ldc);
}

// dual-direction variant: blockIdx.z selects fw/bw pointer set (fills the grid)
template<int BM,int BN,int BK,int NWM,int NWN,int EPI>
__global__ __launch_bounds__(256) void gemm_mfma_dual(
    const float* __restrict__ Af, const float* __restrict__ Ab,
    const float* __restrict__ Wf, const float* __restrict__ Wb,
    const float* __restrict__ biasf, const float* __restrict__ biasb,
    float* __restrict__ Cf, float* __restrict__ Cb,
    int K, int lda, int ldw, int ldc)
{
    const int d = blockIdx.z;
    gemm_body<BM,BN,BK,NWM,NWN,EPI>(d ? Ab : Af, nullptr, d ? Wb : Wf,
                                    d ? biasb : biasf, d ? Cb : Cf, K, lda, ldw, ldc);
}

// ---------- depthwise causal conv(K=4) + SiLU; dir=1 reads u reversed, outputs reversed ----------
__global__ __launch_bounds__(256) void conv_silu_kernel(
    const float* __restrict__ uxb,
    const float* __restrict__ w_f, const float* __restrict__ b_f,
    const float* __restrict__ w_b, const float* __restrict__ b_b,
    float* __restrict__ uc_f, float* __restrict__ uc_b)
{
    const int dir = blockIdx.y;
    const float* __restrict__ w    = dir ? w_b : w_f;
    const float* __restrict__ bias = dir ? b_b : b_f;
    float* __restrict__ uc         = dir ? uc_b : uc_f;
    int idx = blockIdx.x * 256 + threadIdx.x;       // float4 index
    int e = idx * 4;
    int dq = e & (DINNER - 1);
    int t  = (e / DINNER) & (LSEQ - 1);
    int b  = e / (DINNER * LSEQ);
    float wk[16];
    const float* wp = w + dq * 4;
    #pragma unroll
    for (int i = 0; i < 16; i++) wk[i] = wp[i];
    float4 acc = { bias[dq], bias[dq+1], bias[dq+2], bias[dq+3] };
    #pragma unroll
    for (int k = 0; k < 4; k++){
        int src = t + k - 3;
        if (src >= 0){
            int gt = dir ? (LSEQ - 1 - src) : src;
            float4 uv = *reinterpret_cast<const float4*>(uxb + ((size_t)b * LSEQ + gt) * 2048 + dq);
            acc.x = fmaf(wk[k],      uv.x, acc.x);
            acc.y = fmaf(wk[4 + k],  uv.y, acc.y);
            acc.z = fmaf(wk[8 + k],  uv.z, acc.z);
            acc.w = fmaf(wk[12 + k], uv.w, acc.w);
        }
    }
    acc.x = silu_f(acc.x); acc.y = silu_f(acc.y);
    acc.z = silu_f(acc.z); acc.w = silu_f(acc.w);
    *reinterpret_cast<float4*>(uc + ((size_t)b * LSEQ + t) * DINNER + dq) = acc;
}

// ---------- g = silu(z) ----------
__global__ __launch_bounds__(256) void g_kernel(const float* __restrict__ uxb, float* __restrict__ g)
{
    int i = blockIdx.x * 256 + threadIdx.x;
    int m = i >> 8;
    int dq = (i & 255) << 2;
    float4 z = *reinterpret_cast<const float4*>(uxb + (size_t)m * 2048 + 1024 + dq);
    z.x = silu_f(z.x); z.y = silu_f(z.y); z.z = silu_f(z.z); z.w = silu_f(z.w);
    *reinterpret_cast<float4*>(g + (size_t)m * DINNER + dq) = z;
}

// ---------- selective scan: blocks 0..127 fw, 128..255 bw ----------
__global__ __launch_bounds__(256) void scan_kernel(
    const float* __restrict__ delta_f, const float* __restrict__ delta_b,
    const float* __restrict__ uc_f,    const float* __restrict__ uc_b,
    const float* __restrict__ xdbl_f,  const float* __restrict__ xdbl_b,
    const float* __restrict__ gbuf,
    const float* __restrict__ Alog_f,  const float* __restrict__ Alog_b,
    const float* __restrict__ Dv_f,    const float* __restrict__ Dv_b,
    float* __restrict__ ybuf_f, float* __restrict__ ybuf_b)
{
    constexpr int TC = 64, P = 68;
    __shared__ float sDel[16 * P], sDU[16 * P], sB[16 * P], sC[16 * P], sY[16 * P];
    const int tid = threadIdx.x;
    const int dir = blockIdx.x >> 7;
    const int blk = blockIdx.x & 127;
    const int cl = tid >> 4;
    const int n  = tid & 15;
    const int ch0 = blk << 4;
    const int b  = ch0 >> 10;
    const int d0 = ch0 & 1023;
    const float* __restrict__ delta = dir ? delta_b : delta_f;
    const float* __restrict__ uc    = dir ? uc_b    : uc_f;
    const float* __restrict__ xdbl  = dir ? xdbl_b  : xdbl_f;
    const float* __restrict__ Alog  = dir ? Alog_b  : Alog_f;
    const float* __restrict__ Dv    = dir ? Dv_b    : Dv_f;
    float* __restrict__ ybuf        = dir ? ybuf_b  : ybuf_f;

    const float L2E = 1.4426950408889634f;
    const float A2 = -fast_exp2(Alog[(d0 + cl) * NSTATE + n] * L2E) * L2E;
    float h = 0.f;
    const int sc = tid & 15;
    const int st = tid >> 4;
    const size_t rb = (size_t)b * LSEQ;

    for (int t0 = 0; t0 < LSEQ; t0 += TC){
        #pragma unroll
        for (int tt = 0; tt < TC; tt += 16){
            int t = st + tt;
            size_t m = rb + t0 + t;
            float dl = delta[m * DINNER + d0 + sc];
            float uv = uc[m * DINNER + d0 + sc];
            sDel[sc * P + t] = dl;
            sDU [sc * P + t] = dl * uv;
            sB  [sc * P + t] = xdbl[m * 64 + 32 + sc];
            sC  [sc * P + t] = xdbl[m * 64 + 48 + sc];
        }
        __syncthreads();
        const float* pD = sDel + cl * P;
        const float* pU = sDU  + cl * P;
        const float* pB = sB   + n  * P;
        const float* pC = sC   + n  * P;
        for (int tq = 0; tq < TC; tq += 4){
            float4 dv  = *reinterpret_cast<const float4*>(pD + tq);
            float4 duv = *reinterpret_cast<const float4*>(pU + tq);
            float4 Bv  = *reinterpret_cast<const float4*>(pB + tq);
            float4 Cv  = *reinterpret_cast<const float4*>(pC + tq);
            float4 py;
            {
                float dA = fast_exp2(dv.x * A2);
                h = fmaf(dA, h, duv.x * Bv.x);
                float p = h * Cv.x;
                p += dpp_rot<0x128>(p); p += dpp_rot<0x124>(p);
                p += dpp_rot<0x122>(p); p += dpp_rot<0x121>(p);
                py.x = p;
            }
            {
                float dA = fast_exp2(dv.y * A2);
                h = fmaf(dA, h, duv.y * Bv.y);
                float p = h * Cv.y;
                p += dpp_rot<0x128>(p); p += dpp_rot<0x124>(p);
                p += dpp_rot<0x122>(p); p += dpp_rot<0x121>(p);
                py.y = p;
            }
            {
                float dA = fast_exp2(dv.z * A2);
                h = fmaf(dA, h, duv.z * Bv.z);
                float p = h * Cv.z;
                p += dpp_rot<0x128>(p); p += dpp_rot<0x124>(p);
                p += dpp_rot<0x122>(p); p += dpp_rot<0x121>(p);
                py.z = p;
            }
            {
                float dA = fast_exp2(dv.w * A2);
                h = fmaf(dA, h, duv.w * Bv.w);
                float p = h * Cv.w;
                p += dpp_rot<0x128>(p); p += dpp_rot<0x124>(p);
                p += dpp_rot<0x122>(p); p += dpp_rot<0x121>(p);
                py.w = p;
            }
            if (n == 0) *reinterpret_cast<float4*>(sY + cl * P + tq) = py;
        }
        __syncthreads();
        #pragma unroll
        for (int tt = 0; tt < TC; tt += 16){
            int t = st + tt;
            int gt = t0 + t;
            size_t m = rb + gt;
            float y = sY[sc * P + t] + uc[m * DINNER + d0 + sc] * Dv[d0 + sc];
            int ot = dir ? (LSEQ - 1 - gt) : gt;
            size_t mo = rb + ot;
            float gv = gbuf[mo * DINNER + d0 + sc];
            ybuf[mo * DINNER + d0 + sc] = y * gv;
        }
        __syncthreads();
    }
}

// ---------- host launch ----------
extern "C" void kernel_launch(void* const* d_in, const int* in_sizes, int n_in,
                              void* d_out, int out_size, void* d_ws, size_t ws_size,
                              hipStream_t stream)
{
    const float* x         = (const float*)d_in[0];
    const float* ln1_w     = (const float*)d_in[1];
    const float* ln1_b     = (const float*)d_in[2];
    const float* ln2_w     = (const float*)d_in[3];
    const float* ln2_b     = (const float*)d_in[4];
    const float* in_proj_w = (const float*)d_in[5];
    const float* conv_w_f  = (const float*)d_in[6];
    const float* conv_b_f  = (const float*)d_in[7];
    const float* xproj_f   = (const float*)d_in[8];
    const float* dt_w_f    = (const float*)d_in[9];
    const float* dt_b_f    = (const float*)d_in[10];
    const float* Alog_f    = (const float*)d_in[11];
    const float* D_f       = (const float*)d_in[12];
    const float* conv_w_b  = (const float*)d_in[13];
    const float* conv_b_b  = (const float*)d_in[14];
    const float* xproj_b   = (const float*)d_in[15];
    const float* dt_w_b    = (const float*)d_in[16];
    const float* dt_b_b    = (const float*)d_in[17];
    const float* Alog_b    = (const float*)d_in[18];
    const float* D_b       = (const float*)d_in[19];
    const float* outproj   = (const float*)d_in[20];
    float* out = (float*)d_out;

    float* ws      = (float*)d_ws;
    float* xn      = ws;                    // 2,097,152 (reused as out_pre)
    float* out_pre = ws;
    float* uxb     = ws + 2097152;          // 8,388,608 [u | z]
    float* delta_f = uxb;                   // alias (all ux readers done before write)
    float* delta_b = uxb + 4194304;
    float* uc_f    = uxb + 8388608;
    float* uc_b    = uc_f + 4194304;
    float* gbuf    = uc_b + 4194304;
    float* xdbl_f  = gbuf + 4194304;
    float* xdbl_b  = xdbl_f + 262144;
    float* ybuf_f  = xdbl_b + 262144;
    float* ybuf_b  = ybuf_f + 4194304;

    // 1. LN1
    ln_kernel<<<MROWS, 256, 0, stream>>>(x, nullptr, ln1_w, ln1_b, xn);
    // 2. in_proj: ux[4096,2048] = xn @ in_proj_w^T  (bf16 MFMA)
    gemm_mfma<128,128,32,2,2,0><<<dim3(16,32), 256, 0, stream>>>(
        xn, nullptr, in_proj_w, nullptr, uxb, 512, 512, 512, 2048);
    // 3. causal conv + silu (fw & bw)
    conv_silu_kernel<<<dim3(4096,2), 256, 0, stream>>>(
        uxb, conv_w_f, conv_b_f, conv_w_b, conv_b_b, uc_f, uc_b);
    // 4. g = silu(z)
    g_kernel<<<4096, 256, 0, stream>>>(uxb, gbuf);
    // 5. x_proj fw+bw fused: xdbl[4096,64] = uc @ x_proj_w^T
    gemm_mfma_dual<64,64,32,2,2,0><<<dim3(1,64,2), 256, 0, stream>>>(
        uc_f, uc_b, xproj_f, xproj_b, nullptr, nullptr, xdbl_f, xdbl_b,
        1024, 1024, 1024, 64);
    // 6. delta = softplus(xdbl[:, :32] @ dt_w^T + dt_b)  (K=32: single MFMA step)
    gemm_mfma_dual<128,128,32,2,2,1><<<dim3(8,32,2), 256, 0, stream>>>(
        xdbl_f, xdbl_b, dt_w_f, dt_w_b, dt_b_f, dt_b_b, delta_f, delta_b,
        32, 64, 32, 1024);
    // 7. selective scan, fw+bw concurrent, writes (y + uc*D)*g
    scan_kernel<<<256, 256, 0, stream>>>(
        delta_f, delta_b, uc_f, uc_b, xdbl_f, xdbl_b, gbuf,
        Alog_f, Alog_b, D_f, D_b, ybuf_f, ybuf_b);
    // 8. out_proj: out_pre = (ybuf_f + ybuf_b) @ out_proj_w^T  (256-block grid)
    gemm_mfma<128,64,32,4,1,0><<<dim3(8,32), 256, 0, stream>>>(
        ybuf_f, ybuf_b, outproj, nullptr, out_pre, 1024, 1024, 1024, 512);
    // 9. LN2(out + x) -> d_out
    ln_kernel<<<MROWS, 256, 0, stream>>>(out_pre, x, ln2_w, ln2_b, out);
}

// Round 3
// 346.348 us; speedup vs baseline: 2.2959x; 1.2036x over previous
//
#include <hip/hip_runtime.h>

#define LSEQ   2048
#define NBATCH 2
#define DMODEL 512
#define DINNER 1024
#define NSTATE 16
#define MROWS  4096   // NBATCH*LSEQ
#define SSEG   16     // segments per sequence (scan parallelism)
#define TSEG   128    // LSEQ / SSEG

typedef __bf16 bf16x8 __attribute__((ext_vector_type(8)));
typedef short  short8 __attribute__((ext_vector_type(8)));
typedef float  f32x4  __attribute__((ext_vector_type(4)));

// ---------- fast math helpers ----------
__device__ __forceinline__ float fast_exp2(float x){
#if __has_builtin(__builtin_amdgcn_exp2f)
    return __builtin_amdgcn_exp2f(x);
#else
    return exp2f(x);
#endif
}
__device__ __forceinline__ float fast_log2(float x){
#if __has_builtin(__builtin_amdgcn_logf)
    return __builtin_amdgcn_logf(x);
#else
    return log2f(x);
#endif
}
__device__ __forceinline__ float fast_rcp(float x){
#if __has_builtin(__builtin_amdgcn_rcpf)
    return __builtin_amdgcn_rcpf(x);
#else
    return 1.f/x;
#endif
}
__device__ __forceinline__ float silu_f(float x){
    float e = fast_exp2(-x * 1.4426950408889634f);
    return x * fast_rcp(1.f + e);
}
__device__ __forceinline__ float softplus_f(float x){
    if (x > 20.f) return x;
    float e = fast_exp2(x * 1.4426950408889634f);
    return 0.6931471805599453f * fast_log2(1.f + e);
}
// fp32 -> bf16 round-nearest-even (inputs are finite)
__device__ __forceinline__ unsigned short f2bf(float f){
    unsigned u = __builtin_bit_cast(unsigned, f);
    u += 0x7FFFu + ((u >> 16) & 1u);
    return (unsigned short)(u >> 16);
}
// DPP rotate-within-row16 (VALU-pipe 16-lane reduction)
template<int CTRL>
__device__ __forceinline__ float dpp_rot(float x){
    int r = __builtin_amdgcn_update_dpp(0, __builtin_bit_cast(int, x), CTRL, 0xF, 0xF, true);
    return __builtin_bit_cast(float, r);
}

// ---------- LayerNorm (one row of 512 per block; optional residual) ----------
__global__ __launch_bounds__(256) void ln_kernel(
    const float* __restrict__ in, const float* __restrict__ res,
    const float* __restrict__ w, const float* __restrict__ bsc,
    float* __restrict__ out)
{
    int row = blockIdx.x;
    int tid = threadIdx.x;
    size_t base = (size_t)row * DMODEL;
    float v0 = in[base + tid], v1 = in[base + tid + 256];
    if (res){ v0 += res[base + tid]; v1 += res[base + tid + 256]; }
    float s = v0 + v1, s2 = v0*v0 + v1*v1;
    #pragma unroll
    for (int off = 32; off > 0; off >>= 1){
        s  += __shfl_down(s,  off, 64);
        s2 += __shfl_down(s2, off, 64);
    }
    __shared__ float red[8];
    int wid = tid >> 6;
    if ((tid & 63) == 0){ red[wid] = s; red[4 + wid] = s2; }
    __syncthreads();
    if (tid == 0){
        float a = red[0] + red[1] + red[2] + red[3];
        float c = red[4] + red[5] + red[6] + red[7];
        float m = a * (1.f / DMODEL);
        red[0] = m;
        red[1] = c * (1.f / DMODEL) - m * m;
    }
    __syncthreads();
    float mean = red[0];
    float rs = rsqrtf(red[1] + 1e-5f);
    out[base + tid]       = (v0 - mean) * rs * w[tid]       + bsc[tid];
    out[base + tid + 256] = (v1 - mean) * rs * w[tid + 256] + bsc[tid + 256];
}

// ---------- bf16 MFMA GEMM body: C[M,N] = (A (+A2)) @ W^T ----------
template<int BM,int BN,int BK,int NWM,int NWN,int EPI>
__device__ __forceinline__ void gemm_body(
    const float* __restrict__ A, const float* __restrict__ A2,
    const float* __restrict__ W, const float* __restrict__ bias,
    float* __restrict__ C, int K, int lda, int ldw, int ldc)
{
    constexpr int BKp = BK + 8;
    constexpr int FM  = BM / (16 * NWM);
    constexpr int FN  = BN / (16 * NWN);
    static_assert(NWM * NWN == 4, "4 waves");
    static_assert(BK % 32 == 0, "K-step");
    __shared__ unsigned short As[BM * BKp];
    __shared__ unsigned short Ws[BN * BKp];
    const int tid  = threadIdx.x;
    const int wave = tid >> 6, lane = tid & 63;
    const int row16 = lane & 15, q = lane >> 4;
    const int wm = (wave / NWN) * (FM * 16);
    const int wn = (wave % NWN) * (FN * 16);
    const int m0 = blockIdx.y * BM;
    const int n0 = blockIdx.x * BN;
    f32x4 acc[FM][FN] = {};

    for (int k0 = 0; k0 < K; k0 += BK){
        #pragma unroll
        for (int idx = tid * 8; idx < BM * BK; idx += 2048){
            int r = idx / BK, c = idx % BK;
            const float* g = A + (size_t)(m0 + r) * lda + k0 + c;
            float4 v0 = *(const float4*)g, v1 = *(const float4*)(g + 4);
            if (A2){
                const float* g2 = A2 + (size_t)(m0 + r) * lda + k0 + c;
                float4 w0 = *(const float4*)g2, w1 = *(const float4*)(g2 + 4);
                v0.x += w0.x; v0.y += w0.y; v0.z += w0.z; v0.w += w0.w;
                v1.x += w1.x; v1.y += w1.y; v1.z += w1.z; v1.w += w1.w;
            }
            short8 s;
            s[0] = (short)f2bf(v0.x); s[1] = (short)f2bf(v0.y);
            s[2] = (short)f2bf(v0.z); s[3] = (short)f2bf(v0.w);
            s[4] = (short)f2bf(v1.x); s[5] = (short)f2bf(v1.y);
            s[6] = (short)f2bf(v1.z); s[7] = (short)f2bf(v1.w);
            *(short8*)(As + r * BKp + c) = s;
        }
        #pragma unroll
        for (int idx = tid * 8; idx < BN * BK; idx += 2048){
            int r = idx / BK, c = idx % BK;
            const float* g = W + (size_t)(n0 + r) * ldw + k0 + c;
            float4 v0 = *(const float4*)g, v1 = *(const float4*)(g + 4);
            short8 s;
            s[0] = (short)f2bf(v0.x); s[1] = (short)f2bf(v0.y);
            s[2] = (short)f2bf(v0.z); s[3] = (short)f2bf(v0.w);
            s[4] = (short)f2bf(v1.x); s[5] = (short)f2bf(v1.y);
            s[6] = (short)f2bf(v1.z); s[7] = (short)f2bf(v1.w);
            *(short8*)(Ws + r * BKp + c) = s;
        }
        __syncthreads();
        #pragma unroll
        for (int ks = 0; ks < BK; ks += 32){
            bf16x8 af[FM], bfr[FN];
            #pragma unroll
            for (int i = 0; i < FM; i++){
                const unsigned short* p = As + (wm + i * 16 + row16) * BKp + ks + q * 8;
                af[i] = __builtin_bit_cast(bf16x8, *(const short8*)p);
            }
            #pragma unroll
            for (int j = 0; j < FN; j++){
                const unsigned short* p = Ws + (wn + j * 16 + row16) * BKp + ks + q * 8;
                bfr[j] = __builtin_bit_cast(bf16x8, *(const short8*)p);
            }
            #pragma unroll
            for (int i = 0; i < FM; i++)
                #pragma unroll
                for (int j = 0; j < FN; j++)
                    acc[i][j] = __builtin_amdgcn_mfma_f32_16x16x32_bf16(af[i], bfr[j], acc[i][j], 0, 0, 0);
        }
        __syncthreads();
    }
    #pragma unroll
    for (int j = 0; j < FN; j++){
        int n = n0 + wn + j * 16 + row16;
        float bv = (EPI == 1) ? bias[n] : 0.f;
        #pragma unroll
        for (int i = 0; i < FM; i++){
            #pragma unroll
            for (int r = 0; r < 4; r++){
                int m = m0 + wm + i * 16 + q * 4 + r;
                float v = acc[i][j][r];
                if (EPI == 1) v = softplus_f(v + bv);
                C[(size_t)m * ldc + n] = v;
            }
        }
    }
}

template<int BM,int BN,int BK,int NWM,int NWN,int EPI>
__global__ __launch_bounds__(256) void gemm_mfma(
    const float* __restrict__ A, const float* __restrict__ A2,
    const float* __restrict__ W, const float* __restrict__ bias,
    float* __restrict__ C, int K, int lda, int ldw, int ldc)
{
    gemm_body<BM,BN,BK,NWM,NWN,EPI>(A, A2, W, bias, C, K, lda, ldw, ldc);
}

template<int BM,int BN,int BK,int NWM,int NWN,int EPI>
__global__ __launch_bounds__(256) void gemm_mfma_dual(
    const float* __restrict__ Af, const float* __restrict__ Ab,
    const float* __restrict__ Wf, const float* __restrict__ Wb,
    const float* __restrict__ biasf, const float* __restrict__ biasb,
    float* __restrict__ Cf, float* __restrict__ Cb,
    int K, int lda, int ldw, int ldc)
{
    const int d = blockIdx.z;
    gemm_body<BM,BN,BK,NWM,NWN,EPI>(d ? Ab : Af, nullptr, d ? Wb : Wf,
                                    d ? biasb : biasf, d ? Cb : Cf, K, lda, ldw, ldc);
}

// ---------- depthwise causal conv(K=4) + SiLU ----------
__global__ __launch_bounds__(256) void conv_silu_kernel(
    const float* __restrict__ uxb,
    const float* __restrict__ w_f, const float* __restrict__ b_f,
    const float* __restrict__ w_b, const float* __restrict__ b_b,
    float* __restrict__ uc_f, float* __restrict__ uc_b)
{
    const int dir = blockIdx.y;
    const float* __restrict__ w    = dir ? w_b : w_f;
    const float* __restrict__ bias = dir ? b_b : b_f;
    float* __restrict__ uc         = dir ? uc_b : uc_f;
    int idx = blockIdx.x * 256 + threadIdx.x;
    int e = idx * 4;
    int dq = e & (DINNER - 1);
    int t  = (e / DINNER) & (LSEQ - 1);
    int b  = e / (DINNER * LSEQ);
    float wk[16];
    const float* wp = w + dq * 4;
    #pragma unroll
    for (int i = 0; i < 16; i++) wk[i] = wp[i];
    float4 acc = { bias[dq], bias[dq+1], bias[dq+2], bias[dq+3] };
    #pragma unroll
    for (int k = 0; k < 4; k++){
        int src = t + k - 3;
        if (src >= 0){
            int gt = dir ? (LSEQ - 1 - src) : src;
            float4 uv = *reinterpret_cast<const float4*>(uxb + ((size_t)b * LSEQ + gt) * 2048 + dq);
            acc.x = fmaf(wk[k],      uv.x, acc.x);
            acc.y = fmaf(wk[4 + k],  uv.y, acc.y);
            acc.z = fmaf(wk[8 + k],  uv.z, acc.z);
            acc.w = fmaf(wk[12 + k], uv.w, acc.w);
        }
    }
    acc.x = silu_f(acc.x); acc.y = silu_f(acc.y);
    acc.z = silu_f(acc.z); acc.w = silu_f(acc.w);
    *reinterpret_cast<float4*>(uc + ((size_t)b * LSEQ + t) * DINNER + dq) = acc;
}

// ---------- g = silu(z) ----------
__global__ __launch_bounds__(256) void g_kernel(const float* __restrict__ uxb, float* __restrict__ g)
{
    int i = blockIdx.x * 256 + threadIdx.x;
    int m = i >> 8;
    int dq = (i & 255) << 2;
    float4 z = *reinterpret_cast<const float4*>(uxb + (size_t)m * 2048 + 1024 + dq);
    z.x = silu_f(z.x); z.y = silu_f(z.y); z.z = silu_f(z.z); z.w = silu_f(z.w);
    *reinterpret_cast<float4*>(g + (size_t)m * DINNER + dq) = z;
}

// ================= chunked selective scan (3 kernels) =================
// grid (pass1/pass2): (SSEG segments, 128 channel-blocks, 2 dirs)
// hseg layout: [(dir*2048 + ch) * SSEG + s] * 16 + n
// dsum layout: [(dir*2048 + ch) * SSEG + s]

// pass1: per-segment local scan from h0=0 -> hseg; per-channel sum(delta) -> dsum
__global__ __launch_bounds__(256) void scan_pass1(
    const float* __restrict__ delta_f, const float* __restrict__ delta_b,
    const float* __restrict__ uc_f,    const float* __restrict__ uc_b,
    const float* __restrict__ xdbl_f,  const float* __restrict__ xdbl_b,
    const float* __restrict__ Alog_f,  const float* __restrict__ Alog_b,
    float* __restrict__ hseg, float* __restrict__ dsum)
{
    constexpr int TC = 64, P = 68;
    __shared__ float sDel[16 * P], sDU[16 * P], sB[16 * P];
    __shared__ float sDS[16 * 17];
    const int tid = threadIdx.x;
    const int s   = blockIdx.x;
    const int blk = blockIdx.y;
    const int dir = blockIdx.z;
    const int cl = tid >> 4;          // compute role: channel in block
    const int n  = tid & 15;          // state
    const int sc = tid & 15;          // staging role: channel
    const int st = tid >> 4;          // staging role: t sub-index
    const int ch0 = blk << 4;
    const int b  = ch0 >> 10;
    const int d0 = ch0 & 1023;
    const float* __restrict__ delta = dir ? delta_b : delta_f;
    const float* __restrict__ uc    = dir ? uc_b    : uc_f;
    const float* __restrict__ xdbl  = dir ? xdbl_b  : xdbl_f;
    const float* __restrict__ Alog  = dir ? Alog_b  : Alog_f;

    const float L2E = 1.4426950408889634f;
    const float A2 = -fast_exp2(Alog[(d0 + cl) * NSTATE + n] * L2E) * L2E;
    float h = 0.f;
    float dpart = 0.f;
    const size_t rb = (size_t)b * LSEQ;
    const int tb = s * TSEG;

    for (int t0 = tb; t0 < tb + TSEG; t0 += TC){
        #pragma unroll
        for (int tt = 0; tt < TC; tt += 16){
            int t = st + tt;
            size_t m = rb + t0 + t;
            float dl = delta[m * DINNER + d0 + sc];
            float uv = uc[m * DINNER + d0 + sc];
            sDel[sc * P + t] = dl;
            sDU [sc * P + t] = dl * uv;
            sB  [sc * P + t] = xdbl[m * 64 + 32 + sc];
            dpart += dl;
        }
        __syncthreads();
        const float* pD = sDel + cl * P;
        const float* pU = sDU  + cl * P;
        const float* pB = sB   + n  * P;
        #pragma unroll 4
        for (int tq = 0; tq < TC; tq += 4){
            float4 dv  = *reinterpret_cast<const float4*>(pD + tq);
            float4 duv = *reinterpret_cast<const float4*>(pU + tq);
            float4 Bv  = *reinterpret_cast<const float4*>(pB + tq);
            h = fmaf(fast_exp2(dv.x * A2), h, duv.x * Bv.x);
            h = fmaf(fast_exp2(dv.y * A2), h, duv.y * Bv.y);
            h = fmaf(fast_exp2(dv.z * A2), h, duv.z * Bv.z);
            h = fmaf(fast_exp2(dv.w * A2), h, duv.w * Bv.w);
        }
        __syncthreads();
    }
    // local final state
    int chd = (dir << 11) + ch0 + cl;               // dir*2048 + channel
    hseg[((size_t)chd * SSEG + s) * 16 + n] = h;
    // per-channel delta sum: partials are per staging lane (sc, st)
    sDS[sc * 17 + st] = dpart;
    __syncthreads();
    float p = sDS[cl * 17 + n];
    p += dpp_rot<0x128>(p); p += dpp_rot<0x124>(p);
    p += dpp_rot<0x122>(p); p += dpp_rot<0x121>(p);
    if (n == 0) dsum[(size_t)chd * SSEG + s] = p;
}

// combine: serial prefix over segments; overwrites hseg with segment INITIAL states
__global__ __launch_bounds__(256) void scan_combine(
    const float* __restrict__ dsum,
    const float* __restrict__ Alog_f, const float* __restrict__ Alog_b,
    float* __restrict__ hseg)
{
    int idx = blockIdx.x * 256 + threadIdx.x;       // (dir*2048 + ch)*16 + n
    int n   = idx & 15;
    int chd = idx >> 4;                              // [0, 4096)
    int dir = chd >> 11;
    int ch  = chd & 2047;
    int d   = ch & 1023;
    const float* __restrict__ Alog = dir ? Alog_b : Alog_f;
    const float L2E = 1.4426950408889634f;
    const float A2 = -fast_exp2(Alog[d * NSTATE + n] * L2E) * L2E;
    float H = 0.f;
    #pragma unroll
    for (int s = 0; s < SSEG; s++){
        size_t base = ((size_t)chd * SSEG + s) * 16 + n;
        float hv = hseg[base];
        float ds = dsum[(size_t)chd * SSEG + s];
        hseg[base] = H;                              // initial state for segment s
        H = fmaf(fast_exp2(A2 * ds), H, hv);
    }
}

// pass2: re-run recurrence from hseg initial states, emit y = (scan + u*D)*g
__global__ __launch_bounds__(256) void scan_pass2(
    const float* __restrict__ delta_f, const float* __restrict__ delta_b,
    const float* __restrict__ uc_f,    const float* __restrict__ uc_b,
    const float* __restrict__ xdbl_f,  const float* __restrict__ xdbl_b,
    const float* __restrict__ gbuf,
    const float* __restrict__ Alog_f,  const float* __restrict__ Alog_b,
    const float* __restrict__ Dv_f,    const float* __restrict__ Dv_b,
    const float* __restrict__ hseg,
    float* __restrict__ ybuf_f, float* __restrict__ ybuf_b)
{
    constexpr int TC = 64, P = 68;
    __shared__ float sDel[16 * P], sDU[16 * P], sB[16 * P], sC[16 * P], sY[16 * P], sUD[16 * P];
    const int tid = threadIdx.x;
    const int s   = blockIdx.x;
    const int blk = blockIdx.y;
    const int dir = blockIdx.z;
    const int cl = tid >> 4;
    const int n  = tid & 15;
    const int sc = tid & 15;
    const int st = tid >> 4;
    const int ch0 = blk << 4;
    const int b  = ch0 >> 10;
    const int d0 = ch0 & 1023;
    const float* __restrict__ delta = dir ? delta_b : delta_f;
    const float* __restrict__ uc    = dir ? uc_b    : uc_f;
    const float* __restrict__ xdbl  = dir ? xdbl_b  : xdbl_f;
    const float* __restrict__ Alog  = dir ? Alog_b  : Alog_f;
    const float* __restrict__ Dv    = dir ? Dv_b    : Dv_f;
    float* __restrict__ ybuf        = dir ? ybuf_b  : ybuf_f;

    const float L2E = 1.4426950408889634f;
    const float A2 = -fast_exp2(Alog[(d0 + cl) * NSTATE + n] * L2E) * L2E;
    const float Dval = Dv[d0 + sc];
    const int chd = (dir << 11) + ch0 + cl;
    float h = hseg[((size_t)chd * SSEG + s) * 16 + n];
    const size_t rb = (size_t)b * LSEQ;
    const int tb = s * TSEG;

    for (int t0 = tb; t0 < tb + TSEG; t0 += TC){
        #pragma unroll
        for (int tt = 0; tt < TC; tt += 16){
            int t = st + tt;
            size_t m = rb + t0 + t;
            float dl = delta[m * DINNER + d0 + sc];
            float uv = uc[m * DINNER + d0 + sc];
            sDel[sc * P + t] = dl;
            sDU [sc * P + t] = dl * uv;
            sUD [sc * P + t] = uv * Dval;
            sB  [sc * P + t] = xdbl[m * 64 + 32 + sc];
            sC  [sc * P + t] = xdbl[m * 64 + 48 + sc];
        }
        __syncthreads();
        const float* pD = sDel + cl * P;
        const float* pU = sDU  + cl * P;
        const float* pB = sB   + n  * P;
        const float* pC = sC   + n  * P;
        for (int tq = 0; tq < TC; tq += 4){
            float4 dv  = *reinterpret_cast<const float4*>(pD + tq);
            float4 duv = *reinterpret_cast<const float4*>(pU + tq);
            float4 Bv  = *reinterpret_cast<const float4*>(pB + tq);
            float4 Cv  = *reinterpret_cast<const float4*>(pC + tq);
            float4 py;
            {
                h = fmaf(fast_exp2(dv.x * A2), h, duv.x * Bv.x);
                float p = h * Cv.x;
                p += dpp_rot<0x128>(p); p += dpp_rot<0x124>(p);
                p += dpp_rot<0x122>(p); p += dpp_rot<0x121>(p);
                py.x = p;
            }
            {
                h = fmaf(fast_exp2(dv.y * A2), h, duv.y * Bv.y);
                float p = h * Cv.y;
                p += dpp_rot<0x128>(p); p += dpp_rot<0x124>(p);
                p += dpp_rot<0x122>(p); p += dpp_rot<0x121>(p);
                py.y = p;
            }
            {
                h = fmaf(fast_exp2(dv.z * A2), h, duv.z * Bv.z);
                float p = h * Cv.z;
                p += dpp_rot<0x128>(p); p += dpp_rot<0x124>(p);
                p += dpp_rot<0x122>(p); p += dpp_rot<0x121>(p);
                py.z = p;
            }
            {
                h = fmaf(fast_exp2(dv.w * A2), h, duv.w * Bv.w);
                float p = h * Cv.w;
                p += dpp_rot<0x128>(p); p += dpp_rot<0x124>(p);
                p += dpp_rot<0x122>(p); p += dpp_rot<0x121>(p);
                py.w = p;
            }
            if (n == 0) *reinterpret_cast<float4*>(sY + cl * P + tq) = py;
        }
        __syncthreads();
        #pragma unroll
        for (int tt = 0; tt < TC; tt += 16){
            int t = st + tt;
            int gt = t0 + t;
            float y = sY[sc * P + t] + sUD[sc * P + t];
            int ot = dir ? (LSEQ - 1 - gt) : gt;
            size_t mo = rb + ot;
            float gv = gbuf[mo * DINNER + d0 + sc];
            ybuf[mo * DINNER + d0 + sc] = y * gv;
        }
        __syncthreads();
    }
}

// ---------- host launch ----------
extern "C" void kernel_launch(void* const* d_in, const int* in_sizes, int n_in,
                              void* d_out, int out_size, void* d_ws, size_t ws_size,
                              hipStream_t stream)
{
    const float* x         = (const float*)d_in[0];
    const float* ln1_w     = (const float*)d_in[1];
    const float* ln1_b     = (const float*)d_in[2];
    const float* ln2_w     = (const float*)d_in[3];
    const float* ln2_b     = (const float*)d_in[4];
    const float* in_proj_w = (const float*)d_in[5];
    const float* conv_w_f  = (const float*)d_in[6];
    const float* conv_b_f  = (const float*)d_in[7];
    const float* xproj_f   = (const float*)d_in[8];
    const float* dt_w_f    = (const float*)d_in[9];
    const float* dt_b_f    = (const float*)d_in[10];
    const float* Alog_f    = (const float*)d_in[11];
    const float* D_f       = (const float*)d_in[12];
    const float* conv_w_b  = (const float*)d_in[13];
    const float* conv_b_b  = (const float*)d_in[14];
    const float* xproj_b   = (const float*)d_in[15];
    const float* dt_w_b    = (const float*)d_in[16];
    const float* dt_b_b    = (const float*)d_in[17];
    const float* Alog_b    = (const float*)d_in[18];
    const float* D_b       = (const float*)d_in[19];
    const float* outproj   = (const float*)d_in[20];
    float* out = (float*)d_out;

    float* ws      = (float*)d_ws;
    float* xn      = ws;                    // LN1 out; dead after in_proj
    float* hseg    = ws;                    // reuses xn region (4 MB < 8 MB)
    float* dsum    = ws + 1048576;
    float* out_pre = ws;                    // written after pass2 consumed hseg
    float* uxb     = ws + 2097152;          // [u | z]
    float* delta_f = uxb;                   // alias (ux dead before delta written)
    float* delta_b = uxb + 4194304;
    float* uc_f    = uxb + 8388608;
    float* uc_b    = uc_f + 4194304;
    float* gbuf    = uc_b + 4194304;
    float* xdbl_f  = gbuf + 4194304;
    float* xdbl_b  = xdbl_f + 262144;
    float* ybuf_f  = xdbl_b + 262144;
    float* ybuf_b  = ybuf_f + 4194304;

    // 1. LN1
    ln_kernel<<<MROWS, 256, 0, stream>>>(x, nullptr, ln1_w, ln1_b, xn);
    // 2. in_proj: ux[4096,2048] = xn @ in_proj_w^T  (bf16 MFMA)
    gemm_mfma<128,128,32,2,2,0><<<dim3(16,32), 256, 0, stream>>>(
        xn, nullptr, in_proj_w, nullptr, uxb, 512, 512, 512, 2048);
    // 3. causal conv + silu (fw & bw)
    conv_silu_kernel<<<dim3(4096,2), 256, 0, stream>>>(
        uxb, conv_w_f, conv_b_f, conv_w_b, conv_b_b, uc_f, uc_b);
    // 4. g = silu(z)
    g_kernel<<<4096, 256, 0, stream>>>(uxb, gbuf);
    // 5. x_proj fw+bw fused
    gemm_mfma_dual<64,64,32,2,2,0><<<dim3(1,64,2), 256, 0, stream>>>(
        uc_f, uc_b, xproj_f, xproj_b, nullptr, nullptr, xdbl_f, xdbl_b,
        1024, 1024, 1024, 64);
    // 6. delta = softplus(xdbl[:, :32] @ dt_w^T + dt_b)
    gemm_mfma_dual<128,128,32,2,2,1><<<dim3(8,32,2), 256, 0, stream>>>(
        xdbl_f, xdbl_b, dt_w_f, dt_w_b, dt_b_f, dt_b_b, delta_f, delta_b,
        32, 64, 32, 1024);
    // 7. chunked selective scan
    scan_pass1<<<dim3(SSEG,128,2), 256, 0, stream>>>(
        delta_f, delta_b, uc_f, uc_b, xdbl_f, xdbl_b, Alog_f, Alog_b, hseg, dsum);
    scan_combine<<<256, 256, 0, stream>>>(dsum, Alog_f, Alog_b, hseg);
    scan_pass2<<<dim3(SSEG,128,2), 256, 0, stream>>>(
        delta_f, delta_b, uc_f, uc_b, xdbl_f, xdbl_b, gbuf,
        Alog_f, Alog_b, D_f, D_b, hseg, ybuf_f, ybuf_b);
    // 8. out_proj: out_pre = (ybuf_f + ybuf_b) @ out_proj_w^T
    gemm_mfma<128,64,32,4,1,0><<<dim3(8,32), 256, 0, stream>>>(
        ybuf_f, ybuf_b, outproj, nullptr, out_pre, 1024, 1024, 1024, 512);
    // 9. LN2(out + x) -> d_out
    ln_kernel<<<MROWS, 256, 0, stream>>>(out_pre, x, ln2_w, ln2_b, out);
}

// Round 4
// 342.517 us; speedup vs baseline: 2.3216x; 1.0112x over previous
//
#include <hip/hip_runtime.h>

#define LSEQ   2048
#define NBATCH 2
#define DMODEL 512
#define DINNER 1024
#define NSTATE 16
#define MROWS  4096   // NBATCH*LSEQ
#define SSEG   32     // segments per sequence
#define TSEG   64     // LSEQ / SSEG

typedef __bf16 bf16x8 __attribute__((ext_vector_type(8)));
typedef short  short8 __attribute__((ext_vector_type(8)));
typedef unsigned short ushort8v __attribute__((ext_vector_type(8)));
typedef float  f32x4  __attribute__((ext_vector_type(4)));

// ---------- fast math helpers ----------
__device__ __forceinline__ float fast_exp2(float x){
#if __has_builtin(__builtin_amdgcn_exp2f)
    return __builtin_amdgcn_exp2f(x);
#else
    return exp2f(x);
#endif
}
__device__ __forceinline__ float fast_log2(float x){
#if __has_builtin(__builtin_amdgcn_logf)
    return __builtin_amdgcn_logf(x);
#else
    return log2f(x);
#endif
}
__device__ __forceinline__ float fast_rcp(float x){
#if __has_builtin(__builtin_amdgcn_rcpf)
    return __builtin_amdgcn_rcpf(x);
#else
    return 1.f/x;
#endif
}
__device__ __forceinline__ float silu_f(float x){
    float e = fast_exp2(-x * 1.4426950408889634f);
    return x * fast_rcp(1.f + e);
}
__device__ __forceinline__ float softplus_f(float x){
    if (x > 20.f) return x;
    float e = fast_exp2(x * 1.4426950408889634f);
    return 0.6931471805599453f * fast_log2(1.f + e);
}
// fp32 -> bf16 round-nearest-even (finite inputs)
__device__ __forceinline__ unsigned short f2bf(float f){
    unsigned u = __builtin_bit_cast(unsigned, f);
    u += 0x7FFFu + ((u >> 16) & 1u);
    return (unsigned short)(u >> 16);
}
__device__ __forceinline__ float bf2f(unsigned short u){
    return __builtin_bit_cast(float, ((unsigned)u) << 16);
}

// ---------- LayerNorm (one row of 512 per block; optional residual) ----------
__global__ __launch_bounds__(256) void ln_kernel(
    const float* __restrict__ in, const float* __restrict__ res,
    const float* __restrict__ w, const float* __restrict__ bsc,
    float* __restrict__ out)
{
    int row = blockIdx.x;
    int tid = threadIdx.x;
    size_t base = (size_t)row * DMODEL;
    float v0 = in[base + tid], v1 = in[base + tid + 256];
    if (res){ v0 += res[base + tid]; v1 += res[base + tid + 256]; }
    float s = v0 + v1, s2 = v0*v0 + v1*v1;
    #pragma unroll
    for (int off = 32; off > 0; off >>= 1){
        s  += __shfl_down(s,  off, 64);
        s2 += __shfl_down(s2, off, 64);
    }
    __shared__ float red[8];
    int wid = tid >> 6;
    if ((tid & 63) == 0){ red[wid] = s; red[4 + wid] = s2; }
    __syncthreads();
    if (tid == 0){
        float a = red[0] + red[1] + red[2] + red[3];
        float c = red[4] + red[5] + red[6] + red[7];
        float m = a * (1.f / DMODEL);
        red[0] = m;
        red[1] = c * (1.f / DMODEL) - m * m;
    }
    __syncthreads();
    float mean = red[0];
    float rs = rsqrtf(red[1] + 1e-5f);
    out[base + tid]       = (v0 - mean) * rs * w[tid]       + bsc[tid];
    out[base + tid + 256] = (v1 - mean) * rs * w[tid + 256] + bsc[tid + 256];
}

// ---------- bf16 MFMA GEMM body: C[M,N] = (A (+A2)) @ W^T ----------
template<int BM,int BN,int BK,int NWM,int NWN,int EPI>
__device__ __forceinline__ void gemm_body(
    const float* __restrict__ A, const float* __restrict__ A2,
    const float* __restrict__ W, const float* __restrict__ bias,
    float* __restrict__ C, int K, int lda, int ldw, int ldc)
{
    constexpr int BKp = BK + 8;
    constexpr int FM  = BM / (16 * NWM);
    constexpr int FN  = BN / (16 * NWN);
    static_assert(NWM * NWN == 4, "4 waves");
    static_assert(BK % 32 == 0, "K-step");
    __shared__ unsigned short As[BM * BKp];
    __shared__ unsigned short Ws[BN * BKp];
    const int tid  = threadIdx.x;
    const int wave = tid >> 6, lane = tid & 63;
    const int row16 = lane & 15, q = lane >> 4;
    const int wm = (wave / NWN) * (FM * 16);
    const int wn = (wave % NWN) * (FN * 16);
    const int m0 = blockIdx.y * BM;
    const int n0 = blockIdx.x * BN;
    f32x4 acc[FM][FN] = {};

    for (int k0 = 0; k0 < K; k0 += BK){
        #pragma unroll
        for (int idx = tid * 8; idx < BM * BK; idx += 2048){
            int r = idx / BK, c = idx % BK;
            const float* g = A + (size_t)(m0 + r) * lda + k0 + c;
            float4 v0 = *(const float4*)g, v1 = *(const float4*)(g + 4);
            if (A2){
                const float* g2 = A2 + (size_t)(m0 + r) * lda + k0 + c;
                float4 w0 = *(const float4*)g2, w1 = *(const float4*)(g2 + 4);
                v0.x += w0.x; v0.y += w0.y; v0.z += w0.z; v0.w += w0.w;
                v1.x += w1.x; v1.y += w1.y; v1.z += w1.z; v1.w += w1.w;
            }
            short8 s;
            s[0] = (short)f2bf(v0.x); s[1] = (short)f2bf(v0.y);
            s[2] = (short)f2bf(v0.z); s[3] = (short)f2bf(v0.w);
            s[4] = (short)f2bf(v1.x); s[5] = (short)f2bf(v1.y);
            s[6] = (short)f2bf(v1.z); s[7] = (short)f2bf(v1.w);
            *(short8*)(As + r * BKp + c) = s;
        }
        #pragma unroll
        for (int idx = tid * 8; idx < BN * BK; idx += 2048){
            int r = idx / BK, c = idx % BK;
            const float* g = W + (size_t)(n0 + r) * ldw + k0 + c;
            float4 v0 = *(const float4*)g, v1 = *(const float4*)(g + 4);
            short8 s;
            s[0] = (short)f2bf(v0.x); s[1] = (short)f2bf(v0.y);
            s[2] = (short)f2bf(v0.z); s[3] = (short)f2bf(v0.w);
            s[4] = (short)f2bf(v1.x); s[5] = (short)f2bf(v1.y);
            s[6] = (short)f2bf(v1.z); s[7] = (short)f2bf(v1.w);
            *(short8*)(Ws + r * BKp + c) = s;
        }
        __syncthreads();
        #pragma unroll
        for (int ks = 0; ks < BK; ks += 32){
            bf16x8 af[FM], bfr[FN];
            #pragma unroll
            for (int i = 0; i < FM; i++){
                const unsigned short* p = As + (wm + i * 16 + row16) * BKp + ks + q * 8;
                af[i] = __builtin_bit_cast(bf16x8, *(const short8*)p);
            }
            #pragma unroll
            for (int j = 0; j < FN; j++){
                const unsigned short* p = Ws + (wn + j * 16 + row16) * BKp + ks + q * 8;
                bfr[j] = __builtin_bit_cast(bf16x8, *(const short8*)p);
            }
            #pragma unroll
            for (int i = 0; i < FM; i++)
                #pragma unroll
                for (int j = 0; j < FN; j++)
                    acc[i][j] = __builtin_amdgcn_mfma_f32_16x16x32_bf16(af[i], bfr[j], acc[i][j], 0, 0, 0);
        }
        __syncthreads();
    }
    #pragma unroll
    for (int j = 0; j < FN; j++){
        int n = n0 + wn + j * 16 + row16;
        float bv = (EPI == 1) ? bias[n] : 0.f;
        #pragma unroll
        for (int i = 0; i < FM; i++){
            #pragma unroll
            for (int r = 0; r < 4; r++){
                int m = m0 + wm + i * 16 + q * 4 + r;
                float v = acc[i][j][r];
                if (EPI == 1) v = softplus_f(v + bv);
                C[(size_t)m * ldc + n] = v;
            }
        }
    }
}

template<int BM,int BN,int BK,int NWM,int NWN,int EPI>
__global__ __launch_bounds__(256) void gemm_mfma(
    const float* __restrict__ A, const float* __restrict__ A2,
    const float* __restrict__ W, const float* __restrict__ bias,
    float* __restrict__ C, int K, int lda, int ldw, int ldc)
{
    gemm_body<BM,BN,BK,NWM,NWN,EPI>(A, A2, W, bias, C, K, lda, ldw, ldc);
}

template<int BM,int BN,int BK,int NWM,int NWN,int EPI>
__global__ __launch_bounds__(256) void gemm_mfma_dual(
    const float* __restrict__ Af, const float* __restrict__ Ab,
    const float* __restrict__ Wf, const float* __restrict__ Wb,
    const float* __restrict__ biasf, const float* __restrict__ biasb,
    float* __restrict__ Cf, float* __restrict__ Cb,
    int K, int lda, int ldw, int ldc)
{
    const int d = blockIdx.z;
    gemm_body<BM,BN,BK,NWM,NWN,EPI>(d ? Ab : Af, nullptr, d ? Wb : Wf,
                                    d ? biasb : biasf, d ? Cb : Cf, K, lda, ldw, ldc);
}

// ---------- out_proj GEMM: A = bf16(ybuf_f) + bf16(ybuf_b) ----------
__global__ __launch_bounds__(256) void gemm_mfma_ybf(
    const unsigned short* __restrict__ Ya, const unsigned short* __restrict__ Yb,
    const float* __restrict__ W, float* __restrict__ C)
{
    constexpr int BM=128, BN=64, BK=32, NWM=4, NWN=1;
    constexpr int BKp = BK + 8;
    constexpr int FM  = BM / (16 * NWM);   // 2
    constexpr int FN  = BN / (16 * NWN);   // 4
    constexpr int K = DINNER, lda = DINNER, ldw = DINNER, ldc = DMODEL;
    __shared__ unsigned short As[BM * BKp];
    __shared__ unsigned short Ws[BN * BKp];
    const int tid  = threadIdx.x;
    const int wave = tid >> 6, lane = tid & 63;
    const int row16 = lane & 15, q = lane >> 4;
    const int wm = (wave / NWN) * (FM * 16);
    const int wn = (wave % NWN) * (FN * 16);
    const int m0 = blockIdx.y * BM;
    const int n0 = blockIdx.x * BN;
    f32x4 acc[FM][FN] = {};

    for (int k0 = 0; k0 < K; k0 += BK){
        #pragma unroll
        for (int idx = tid * 8; idx < BM * BK; idx += 2048){
            int r = idx / BK, c = idx % BK;
            size_t off = (size_t)(m0 + r) * lda + k0 + c;
            ushort8v a = *(const ushort8v*)(Ya + off);
            ushort8v b = *(const ushort8v*)(Yb + off);
            short8 s;
            #pragma unroll
            for (int e = 0; e < 8; e++)
                s[e] = (short)f2bf(bf2f(a[e]) + bf2f(b[e]));
            *(short8*)(As + r * BKp + c) = s;
        }
        { // W stage (BN*BK = 2048 = one sweep)
            int idx = tid * 8;
            int r = idx / BK, c = idx % BK;
            const float* g = W + (size_t)(n0 + r) * ldw + k0 + c;
            float4 v0 = *(const float4*)g, v1 = *(const float4*)(g + 4);
            short8 s;
            s[0] = (short)f2bf(v0.x); s[1] = (short)f2bf(v0.y);
            s[2] = (short)f2bf(v0.z); s[3] = (short)f2bf(v0.w);
            s[4] = (short)f2bf(v1.x); s[5] = (short)f2bf(v1.y);
            s[6] = (short)f2bf(v1.z); s[7] = (short)f2bf(v1.w);
            *(short8*)(Ws + r * BKp + c) = s;
        }
        __syncthreads();
        #pragma unroll
        for (int ks = 0; ks < BK; ks += 32){
            bf16x8 af[FM], bfr[FN];
            #pragma unroll
            for (int i = 0; i < FM; i++){
                const unsigned short* p = As + (wm + i * 16 + row16) * BKp + ks + q * 8;
                af[i] = __builtin_bit_cast(bf16x8, *(const short8*)p);
            }
            #pragma unroll
            for (int j = 0; j < FN; j++){
                const unsigned short* p = Ws + (wn + j * 16 + row16) * BKp + ks + q * 8;
                bfr[j] = __builtin_bit_cast(bf16x8, *(const short8*)p);
            }
            #pragma unroll
            for (int i = 0; i < FM; i++)
                #pragma unroll
                for (int j = 0; j < FN; j++)
                    acc[i][j] = __builtin_amdgcn_mfma_f32_16x16x32_bf16(af[i], bfr[j], acc[i][j], 0, 0, 0);
        }
        __syncthreads();
    }
    #pragma unroll
    for (int j = 0; j < FN; j++){
        int n = n0 + wn + j * 16 + row16;
        #pragma unroll
        for (int i = 0; i < FM; i++){
            #pragma unroll
            for (int r = 0; r < 4; r++){
                int m = m0 + wm + i * 16 + q * 4 + r;
                C[(size_t)m * ldc + n] = acc[i][j][r];
            }
        }
    }
}

// ---------- depthwise causal conv(K=4) + SiLU ----------
__global__ __launch_bounds__(256) void conv_silu_kernel(
    const float* __restrict__ uxb,
    const float* __restrict__ w_f, const float* __restrict__ b_f,
    const float* __restrict__ w_b, const float* __restrict__ b_b,
    float* __restrict__ uc_f, float* __restrict__ uc_b)
{
    const int dir = blockIdx.y;
    const float* __restrict__ w    = dir ? w_b : w_f;
    const float* __restrict__ bias = dir ? b_b : b_f;
    float* __restrict__ uc         = dir ? uc_b : uc_f;
    int idx = blockIdx.x * 256 + threadIdx.x;
    int e = idx * 4;
    int dq = e & (DINNER - 1);
    int t  = (e / DINNER) & (LSEQ - 1);
    int b  = e / (DINNER * LSEQ);
    float wk[16];
    const float* wp = w + dq * 4;
    #pragma unroll
    for (int i = 0; i < 16; i++) wk[i] = wp[i];
    float4 acc = { bias[dq], bias[dq+1], bias[dq+2], bias[dq+3] };
    #pragma unroll
    for (int k = 0; k < 4; k++){
        int src = t + k - 3;
        if (src >= 0){
            int gt = dir ? (LSEQ - 1 - src) : src;
            float4 uv = *reinterpret_cast<const float4*>(uxb + ((size_t)b * LSEQ + gt) * 2048 + dq);
            acc.x = fmaf(wk[k],      uv.x, acc.x);
            acc.y = fmaf(wk[4 + k],  uv.y, acc.y);
            acc.z = fmaf(wk[8 + k],  uv.z, acc.z);
            acc.w = fmaf(wk[12 + k], uv.w, acc.w);
        }
    }
    acc.x = silu_f(acc.x); acc.y = silu_f(acc.y);
    acc.z = silu_f(acc.z); acc.w = silu_f(acc.w);
    *reinterpret_cast<float4*>(uc + ((size_t)b * LSEQ + t) * DINNER + dq) = acc;
}

// ================= register-state chunked scan =================
// lane = channel; 16 states per lane in VGPRs; no LDS.
// wave-unit: (cw, s): cw in [0,64) covers channels cw*64..cw*64+63 (dirs folded), s = segment.
// hseg: [(chd)*SSEG + s]*16 + n ; dsum: [s*4096 + chd]

__global__ __launch_bounds__(256) void scan_pass1(
    const float* __restrict__ delta_f, const float* __restrict__ delta_b,
    const float* __restrict__ uc_f,    const float* __restrict__ uc_b,
    const float* __restrict__ xdbl_f,  const float* __restrict__ xdbl_b,
    const float* __restrict__ Alog_f,  const float* __restrict__ Alog_b,
    float* __restrict__ hseg, float* __restrict__ dsum)
{
    const int wave = threadIdx.x >> 6, lane = threadIdx.x & 63;
    const int unit = blockIdx.x * 4 + wave;      // [0, 2048)
    const int cw = unit >> 5;                    // channel-wave [0,64)
    const int s  = unit & 31;                    // segment
    const int chd0 = cw << 6;
    const int dir = chd0 >> 11;
    const int b   = (chd0 >> 10) & 1;
    const int d0  = chd0 & 1023;
    const int c   = d0 + lane;
    const float* __restrict__ delta = dir ? delta_b : delta_f;
    const float* __restrict__ uc    = dir ? uc_b    : uc_f;
    const float* __restrict__ xdbl  = dir ? xdbl_b  : xdbl_f;
    const float* __restrict__ Alog  = dir ? Alog_b  : Alog_f;
    const float L2E = 1.4426950408889634f;

    float a2[16];
    {
        const float4* ap = (const float4*)(Alog + c * 16);
        float4 t0 = ap[0], t1 = ap[1], t2 = ap[2], t3 = ap[3];
        float tmp[16];
        *(float4*)(tmp+0)=t0; *(float4*)(tmp+4)=t1; *(float4*)(tmp+8)=t2; *(float4*)(tmp+12)=t3;
        #pragma unroll
        for (int n = 0; n < 16; n++) a2[n] = -fast_exp2(tmp[n] * L2E) * L2E;
    }
    float h[16];
    #pragma unroll
    for (int n = 0; n < 16; n++) h[n] = 0.f;
    float dacc = 0.f;
    const size_t rb = (size_t)b * LSEQ;
    const int tb = s * TSEG, te = tb + TSEG;

    // rolling depth-1 prefetch
    size_t m = rb + tb;
    float dl = delta[m * DINNER + c];
    float uv = uc[m * DINNER + c];
    float4 B0, B1, B2, B3;
    { const float4* xb = (const float4*)(xdbl + m * 64 + 32); B0=xb[0]; B1=xb[1]; B2=xb[2]; B3=xb[3]; }

    for (int t = tb; t < te; t++){
        int tn = (t + 1 < te) ? t + 1 : t;
        size_t mn = rb + tn;
        float dl_n = delta[mn * DINNER + c];
        float uv_n = uc[mn * DINNER + c];
        float4 Bn0, Bn1, Bn2, Bn3;
        { const float4* xb = (const float4*)(xdbl + mn * 64 + 32); Bn0=xb[0]; Bn1=xb[1]; Bn2=xb[2]; Bn3=xb[3]; }
        float Ba[16];
        *(float4*)(Ba+0)=B0; *(float4*)(Ba+4)=B1; *(float4*)(Ba+8)=B2; *(float4*)(Ba+12)=B3;
        float du = dl * uv;
        dacc += dl;
        #pragma unroll
        for (int n = 0; n < 16; n++)
            h[n] = fmaf(fast_exp2(dl * a2[n]), h[n], du * Ba[n]);
        dl = dl_n; uv = uv_n; B0=Bn0; B1=Bn1; B2=Bn2; B3=Bn3;
    }
    float* hp = hseg + ((size_t)(chd0 + lane) * SSEG + s) * 16;
    *(float4*)(hp+0)  = (float4){h[0],h[1],h[2],h[3]};
    *(float4*)(hp+4)  = (float4){h[4],h[5],h[6],h[7]};
    *(float4*)(hp+8)  = (float4){h[8],h[9],h[10],h[11]};
    *(float4*)(hp+12) = (float4){h[12],h[13],h[14],h[15]};
    dsum[s * 4096 + chd0 + lane] = dacc;
}

// combine: serial prefix over segments; overwrites hseg with segment INITIAL states
__global__ __launch_bounds__(256) void scan_combine(
    const float* __restrict__ dsum,
    const float* __restrict__ Alog_f, const float* __restrict__ Alog_b,
    float* __restrict__ hseg)
{
    int idx = blockIdx.x * 256 + threadIdx.x;       // chd*16 + n
    int n   = idx & 15;
    int chd = idx >> 4;                              // [0, 4096)
    int dir = chd >> 11;
    int d   = chd & 1023;
    const float* __restrict__ Alog = dir ? Alog_b : Alog_f;
    const float L2E = 1.4426950408889634f;
    const float A2 = -fast_exp2(Alog[d * NSTATE + n] * L2E) * L2E;
    float H = 0.f;
    #pragma unroll
    for (int s = 0; s < SSEG; s++){
        size_t base = ((size_t)chd * SSEG + s) * 16 + n;
        float hv = hseg[base];
        float ds = dsum[s * 4096 + chd];
        hseg[base] = H;
        H = fmaf(fast_exp2(A2 * ds), H, hv);
    }
}

// pass2: recurrence from hseg init, y = (sum_n C_n h_n + u*D) * silu(z), bf16 out
__global__ __launch_bounds__(256) void scan_pass2(
    const float* __restrict__ delta_f, const float* __restrict__ delta_b,
    const float* __restrict__ uc_f,    const float* __restrict__ uc_b,
    const float* __restrict__ xdbl_f,  const float* __restrict__ xdbl_b,
    const float* __restrict__ uxb,
    const float* __restrict__ Alog_f,  const float* __restrict__ Alog_b,
    const float* __restrict__ Dv_f,    const float* __restrict__ Dv_b,
    const float* __restrict__ hseg,
    unsigned short* __restrict__ ybuf_f, unsigned short* __restrict__ ybuf_b)
{
    const int wave = threadIdx.x >> 6, lane = threadIdx.x & 63;
    const int unit = blockIdx.x * 4 + wave;
    const int cw = unit >> 5;
    const int s  = unit & 31;
    const int chd0 = cw << 6;
    const int dir = chd0 >> 11;
    const int b   = (chd0 >> 10) & 1;
    const int d0  = chd0 & 1023;
    const int c   = d0 + lane;
    const float* __restrict__ delta = dir ? delta_b : delta_f;
    const float* __restrict__ uc    = dir ? uc_b    : uc_f;
    const float* __restrict__ xdbl  = dir ? xdbl_b  : xdbl_f;
    const float* __restrict__ Alog  = dir ? Alog_b  : Alog_f;
    const float* __restrict__ Dv    = dir ? Dv_b    : Dv_f;
    unsigned short* __restrict__ ybuf = dir ? ybuf_b : ybuf_f;
    const float L2E = 1.4426950408889634f;

    float a2[16];
    {
        const float4* ap = (const float4*)(Alog + c * 16);
        float4 t0 = ap[0], t1 = ap[1], t2 = ap[2], t3 = ap[3];
        float tmp[16];
        *(float4*)(tmp+0)=t0; *(float4*)(tmp+4)=t1; *(float4*)(tmp+8)=t2; *(float4*)(tmp+12)=t3;
        #pragma unroll
        for (int n = 0; n < 16; n++) a2[n] = -fast_exp2(tmp[n] * L2E) * L2E;
    }
    const float Dval = Dv[c];
    float h[16];
    {
        const float* hp = hseg + ((size_t)(chd0 + lane) * SSEG + s) * 16;
        float4 h0 = *(const float4*)(hp+0), h1 = *(const float4*)(hp+4);
        float4 h2 = *(const float4*)(hp+8), h3 = *(const float4*)(hp+12);
        *(float4*)(h+0)=h0; *(float4*)(h+4)=h1; *(float4*)(h+8)=h2; *(float4*)(h+12)=h3;
    }
    const size_t rb = (size_t)b * LSEQ;
    const int tb = s * TSEG, te = tb + TSEG;

    // rolling depth-1 prefetch (delta, u, z, B, C)
    size_t m = rb + tb;
    int ot0 = dir ? (LSEQ - 1 - tb) : tb;
    size_t mo = rb + ot0;
    float dl = delta[m * DINNER + c];
    float uv = uc[m * DINNER + c];
    float zv = uxb[mo * 2048 + 1024 + c];
    float4 B0,B1,B2,B3, C0,C1,C2,C3;
    { const float4* xb = (const float4*)(xdbl + m * 64 + 32);
      B0=xb[0]; B1=xb[1]; B2=xb[2]; B3=xb[3];
      C0=xb[4]; C1=xb[5]; C2=xb[6]; C3=xb[7]; }

    for (int t = tb; t < te; t++){
        int tn = (t + 1 < te) ? t + 1 : t;
        size_t mn = rb + tn;
        int otn = dir ? (LSEQ - 1 - tn) : tn;
        size_t mon = rb + otn;
        float dl_n = delta[mn * DINNER + c];
        float uv_n = uc[mn * DINNER + c];
        float zv_n = uxb[mon * 2048 + 1024 + c];
        float4 Bn0,Bn1,Bn2,Bn3, Cn0,Cn1,Cn2,Cn3;
        { const float4* xb = (const float4*)(xdbl + mn * 64 + 32);
          Bn0=xb[0]; Bn1=xb[1]; Bn2=xb[2]; Bn3=xb[3];
          Cn0=xb[4]; Cn1=xb[5]; Cn2=xb[6]; Cn3=xb[7]; }

        float Ba[16], Ca[16];
        *(float4*)(Ba+0)=B0; *(float4*)(Ba+4)=B1; *(float4*)(Ba+8)=B2; *(float4*)(Ba+12)=B3;
        *(float4*)(Ca+0)=C0; *(float4*)(Ca+4)=C1; *(float4*)(Ca+8)=C2; *(float4*)(Ca+12)=C3;
        float du = dl * uv;
        float y = uv * Dval;
        #pragma unroll
        for (int n = 0; n < 16; n++){
            h[n] = fmaf(fast_exp2(dl * a2[n]), h[n], du * Ba[n]);
            y = fmaf(h[n], Ca[n], y);
        }
        y *= silu_f(zv);
        int ot = dir ? (LSEQ - 1 - t) : t;
        ybuf[(rb + ot) * DINNER + c] = f2bf(y);

        dl = dl_n; uv = uv_n; zv = zv_n;
        B0=Bn0; B1=Bn1; B2=Bn2; B3=Bn3;
        C0=Cn0; C1=Cn1; C2=Cn2; C3=Cn3;
    }
}

// ---------- host launch ----------
extern "C" void kernel_launch(void* const* d_in, const int* in_sizes, int n_in,
                              void* d_out, int out_size, void* d_ws, size_t ws_size,
                              hipStream_t stream)
{
    const float* x         = (const float*)d_in[0];
    const float* ln1_w     = (const float*)d_in[1];
    const float* ln1_b     = (const float*)d_in[2];
    const float* ln2_w     = (const float*)d_in[3];
    const float* ln2_b     = (const float*)d_in[4];
    const float* in_proj_w = (const float*)d_in[5];
    const float* conv_w_f  = (const float*)d_in[6];
    const float* conv_b_f  = (const float*)d_in[7];
    const float* xproj_f   = (const float*)d_in[8];
    const float* dt_w_f    = (const float*)d_in[9];
    const float* dt_b_f    = (const float*)d_in[10];
    const float* Alog_f    = (const float*)d_in[11];
    const float* D_f       = (const float*)d_in[12];
    const float* conv_w_b  = (const float*)d_in[13];
    const float* conv_b_b  = (const float*)d_in[14];
    const float* xproj_b   = (const float*)d_in[15];
    const float* dt_w_b    = (const float*)d_in[16];
    const float* dt_b_b    = (const float*)d_in[17];
    const float* Alog_b    = (const float*)d_in[18];
    const float* D_b       = (const float*)d_in[19];
    const float* outproj   = (const float*)d_in[20];
    float* out = (float*)d_out;

    // workspace layout (float offsets)
    float* ws      = (float*)d_ws;
    float* xn      = ws;                        // 2,097,152 (dead after in_proj)
    float* hseg    = ws;                        // 4096*32*16 = 2,097,152 (after in_proj)
    float* out_pre = ws;                        // after pass2 (hseg dead)
    float* dsum    = ws + 2097152;              // 131,072
    float* uxb     = ws + 2228224;              // 8,388,608  [u | z] — z live until pass2
    float* delta_f = ws + 10616832;             // 4,194,304
    float* delta_b = ws + 14811136;             // 4,194,304
    float* uc_f    = ws + 19005440;             // 4,194,304
    float* uc_b    = ws + 23199744;             // 4,194,304
    float* xdbl_f  = ws + 27394048;             // 262,144
    float* xdbl_b  = ws + 27656192;             // 262,144
    unsigned short* ybuf_f = (unsigned short*)(ws + 27918336);  // 4,194,304 bf16
    unsigned short* ybuf_b = (unsigned short*)(ws + 30015488);  // 4,194,304 bf16

    // 1. LN1
    ln_kernel<<<MROWS, 256, 0, stream>>>(x, nullptr, ln1_w, ln1_b, xn);
    // 2. in_proj: ux[4096,2048] = xn @ in_proj_w^T  (bf16 MFMA)
    gemm_mfma<128,128,32,2,2,0><<<dim3(16,32), 256, 0, stream>>>(
        xn, nullptr, in_proj_w, nullptr, uxb, 512, 512, 512, 2048);
    // 3. causal conv + silu (fw & bw)
    conv_silu_kernel<<<dim3(4096,2), 256, 0, stream>>>(
        uxb, conv_w_f, conv_b_f, conv_w_b, conv_b_b, uc_f, uc_b);
    // 4. x_proj fw+bw fused
    gemm_mfma_dual<64,64,32,2,2,0><<<dim3(1,64,2), 256, 0, stream>>>(
        uc_f, uc_b, xproj_f, xproj_b, nullptr, nullptr, xdbl_f, xdbl_b,
        1024, 1024, 1024, 64);
    // 5. delta = softplus(xdbl[:, :32] @ dt_w^T + dt_b)
    gemm_mfma_dual<128,128,32,2,2,1><<<dim3(8,32,2), 256, 0, stream>>>(
        xdbl_f, xdbl_b, dt_w_f, dt_w_b, dt_b_f, dt_b_b, delta_f, delta_b,
        32, 64, 32, 1024);
    // 6. chunked selective scan (register-state, no LDS)
    scan_pass1<<<512, 256, 0, stream>>>(
        delta_f, delta_b, uc_f, uc_b, xdbl_f, xdbl_b, Alog_f, Alog_b, hseg, dsum);
    scan_combine<<<256, 256, 0, stream>>>(dsum, Alog_f, Alog_b, hseg);
    scan_pass2<<<512, 256, 0, stream>>>(
        delta_f, delta_b, uc_f, uc_b, xdbl_f, xdbl_b, uxb,
        Alog_f, Alog_b, D_f, D_b, hseg, ybuf_f, ybuf_b);
    // 7. out_proj: out_pre = (ybuf_f + ybuf_b) @ out_proj_w^T  (bf16 A)
    gemm_mfma_ybf<<<dim3(8,32), 256, 0, stream>>>(ybuf_f, ybuf_b, outproj, out_pre);
    // 8. LN2(out + x) -> d_out
    ln_kernel<<<MROWS, 256, 0, stream>>>(out_pre, x, ln2_w, ln2_b, out);
}

// Round 5
// 282.201 us; speedup vs baseline: 2.8178x; 1.2137x over previous
//
#include <hip/hip_runtime.h>

#define LSEQ   2048
#define NBATCH 2
#define DMODEL 512
#define DINNER 1024
#define NSTATE 16
#define MROWS  4096   // NBATCH*LSEQ
#define SSEG   32     // segments per sequence
#define TSEG   64     // LSEQ / SSEG

typedef __bf16 bf16x8 __attribute__((ext_vector_type(8)));
typedef short  short8 __attribute__((ext_vector_type(8)));
typedef unsigned short ushort8v __attribute__((ext_vector_type(8)));
typedef unsigned short ushort4v __attribute__((ext_vector_type(4)));
typedef float  f32x4  __attribute__((ext_vector_type(4)));

// ---------- fast math helpers ----------
__device__ __forceinline__ float fast_exp2(float x){
#if __has_builtin(__builtin_amdgcn_exp2f)
    return __builtin_amdgcn_exp2f(x);
#else
    return exp2f(x);
#endif
}
__device__ __forceinline__ float fast_log2(float x){
#if __has_builtin(__builtin_amdgcn_logf)
    return __builtin_amdgcn_logf(x);
#else
    return log2f(x);
#endif
}
__device__ __forceinline__ float fast_rcp(float x){
#if __has_builtin(__builtin_amdgcn_rcpf)
    return __builtin_amdgcn_rcpf(x);
#else
    return 1.f/x;
#endif
}
__device__ __forceinline__ float silu_f(float x){
    float e = fast_exp2(-x * 1.4426950408889634f);
    return x * fast_rcp(1.f + e);
}
__device__ __forceinline__ float softplus_f(float x){
    if (x > 20.f) return x;
    float e = fast_exp2(x * 1.4426950408889634f);
    return 0.6931471805599453f * fast_log2(1.f + e);
}
// fp32 -> bf16 round-nearest-even (finite inputs)
__device__ __forceinline__ unsigned short f2bf(float f){
    unsigned u = __builtin_bit_cast(unsigned, f);
    u += 0x7FFFu + ((u >> 16) & 1u);
    return (unsigned short)(u >> 16);
}
__device__ __forceinline__ float bf2f(unsigned short u){
    return __builtin_bit_cast(float, ((unsigned)u) << 16);
}

// ---------- weight pre-conversion: 6 fp32 tensors -> bf16 (one launch) ----------
__global__ __launch_bounds__(256) void convert_weights(
    const float* __restrict__ w0, const float* __restrict__ w1,
    const float* __restrict__ w2, const float* __restrict__ w3,
    const float* __restrict__ w4, const float* __restrict__ w5,
    unsigned short* __restrict__ o0, unsigned short* __restrict__ o1,
    unsigned short* __restrict__ o2, unsigned short* __restrict__ o3,
    unsigned short* __restrict__ o4, unsigned short* __restrict__ o5)
{
    int t = blockIdx.x * 256 + threadIdx.x;
    int e = t * 4;
    const float* src; unsigned short* dst; int off;
    if      (e < 1048576){ src = w0; dst = o0; off = e; }
    else if (e < 1572864){ src = w1; dst = o1; off = e - 1048576; }
    else if (e < 1638400){ src = w2; dst = o2; off = e - 1572864; }
    else if (e < 1703936){ src = w3; dst = o3; off = e - 1638400; }
    else if (e < 1736704){ src = w4; dst = o4; off = e - 1703936; }
    else                 { src = w5; dst = o5; off = e - 1736704; }
    float4 v = *(const float4*)(src + off);
    ushort4v s = { f2bf(v.x), f2bf(v.y), f2bf(v.z), f2bf(v.w) };
    *(ushort4v*)(dst + off) = s;
}

// ---------- LayerNorm -> bf16 out (LN1) ----------
__global__ __launch_bounds__(256) void ln_bf_kernel(
    const float* __restrict__ in,
    const float* __restrict__ w, const float* __restrict__ bsc,
    unsigned short* __restrict__ out)
{
    int row = blockIdx.x;
    int tid = threadIdx.x;
    size_t base = (size_t)row * DMODEL;
    float v0 = in[base + tid], v1 = in[base + tid + 256];
    float s = v0 + v1, s2 = v0*v0 + v1*v1;
    #pragma unroll
    for (int off = 32; off > 0; off >>= 1){
        s  += __shfl_down(s,  off, 64);
        s2 += __shfl_down(s2, off, 64);
    }
    __shared__ float red[8];
    int wid = tid >> 6;
    if ((tid & 63) == 0){ red[wid] = s; red[4 + wid] = s2; }
    __syncthreads();
    if (tid == 0){
        float a = red[0] + red[1] + red[2] + red[3];
        float c = red[4] + red[5] + red[6] + red[7];
        float m = a * (1.f / DMODEL);
        red[0] = m;
        red[1] = c * (1.f / DMODEL) - m * m;
    }
    __syncthreads();
    float mean = red[0];
    float rs = rsqrtf(red[1] + 1e-5f);
    out[base + tid]       = f2bf((v0 - mean) * rs * w[tid]       + bsc[tid]);
    out[base + tid + 256] = f2bf((v1 - mean) * rs * w[tid + 256] + bsc[tid + 256]);
}

// ---------- LayerNorm fp32 + residual (LN2) ----------
__global__ __launch_bounds__(256) void ln_kernel(
    const float* __restrict__ in, const float* __restrict__ res,
    const float* __restrict__ w, const float* __restrict__ bsc,
    float* __restrict__ out)
{
    int row = blockIdx.x;
    int tid = threadIdx.x;
    size_t base = (size_t)row * DMODEL;
    float v0 = in[base + tid] + res[base + tid];
    float v1 = in[base + tid + 256] + res[base + tid + 256];
    float s = v0 + v1, s2 = v0*v0 + v1*v1;
    #pragma unroll
    for (int off = 32; off > 0; off >>= 1){
        s  += __shfl_down(s,  off, 64);
        s2 += __shfl_down(s2, off, 64);
    }
    __shared__ float red[8];
    int wid = tid >> 6;
    if ((tid & 63) == 0){ red[wid] = s; red[4 + wid] = s2; }
    __syncthreads();
    if (tid == 0){
        float a = red[0] + red[1] + red[2] + red[3];
        float c = red[4] + red[5] + red[6] + red[7];
        float m = a * (1.f / DMODEL);
        red[0] = m;
        red[1] = c * (1.f / DMODEL) - m * m;
    }
    __syncthreads();
    float mean = red[0];
    float rs = rsqrtf(red[1] + 1e-5f);
    out[base + tid]       = (v0 - mean) * rs * w[tid]       + bsc[tid];
    out[base + tid + 256] = (v1 - mean) * rs * w[tid + 256] + bsc[tid + 256];
}

// ---------- pipelined bf16 GEMM: C[M,N] = A @ W^T (A,W bf16; reg-prefetch dbuf) ----------
// SUM2: A := bf16(A)+bf16(A2) summed in staging. OUTBF: 1 = bf16 C, 0 = fp32 C.
// EPI: 1 = softplus(acc + bias[n]).
template<int BM,int BN,int BK,int NWM,int NWN,int OUTBF,int EPI,bool SUM2>
__device__ __forceinline__ void gemm_bf_body(
    const unsigned short* __restrict__ A, const unsigned short* __restrict__ A2,
    const unsigned short* __restrict__ W, const float* __restrict__ bias,
    void* __restrict__ Cout, int K, int lda, int ldw, int ldc)
{
    constexpr int BKp = BK + 8;                   // +16B pad
    constexpr int FM = BM / (16 * NWM);
    constexpr int FN = BN / (16 * NWN);
    constexpr int AIT = BM * BK / 2048;           // ushort8 loads per thread
    constexpr int WIT = BN * BK / 2048;
    static_assert(NWM * NWN == 4 && BK % 32 == 0 && AIT >= 1 && WIT >= 1, "cfg");
    __shared__ unsigned short As[BM * BKp];
    __shared__ unsigned short Ws[BN * BKp];
    const int tid  = threadIdx.x;
    const int wave = tid >> 6, lane = tid & 63;
    const int row16 = lane & 15, q = lane >> 4;
    const int wm = (wave / NWN) * (FM * 16);
    const int wn = (wave % NWN) * (FN * 16);
    const int m0 = blockIdx.y * BM;
    const int n0 = blockIdx.x * BN;
    f32x4 acc[FM][FN] = {};

    ushort8v ar[AIT], wr[WIT];
    ushort8v a2r[SUM2 ? AIT : 1];
    auto load_tile = [&](int k0){
        #pragma unroll
        for (int i = 0; i < AIT; i++){
            int idx = tid * 8 + i * 2048;
            int r = idx / BK, c = idx % BK;
            ar[i] = *(const ushort8v*)(A + (size_t)(m0 + r) * lda + k0 + c);
            if constexpr (SUM2)
                a2r[i] = *(const ushort8v*)(A2 + (size_t)(m0 + r) * lda + k0 + c);
        }
        #pragma unroll
        for (int i = 0; i < WIT; i++){
            int idx = tid * 8 + i * 2048;
            int r = idx / BK, c = idx % BK;
            wr[i] = *(const ushort8v*)(W + (size_t)(n0 + r) * ldw + k0 + c);
        }
    };
    load_tile(0);

    for (int k0 = 0; k0 < K; k0 += BK){
        #pragma unroll
        for (int i = 0; i < AIT; i++){
            int idx = tid * 8 + i * 2048;
            int r = idx / BK, c = idx % BK;
            ushort8v v = ar[i];
            if constexpr (SUM2){
                ushort8v v2 = a2r[i];
                #pragma unroll
                for (int e = 0; e < 8; e++) v[e] = f2bf(bf2f(v[e]) + bf2f(v2[e]));
            }
            *(ushort8v*)(As + r * BKp + c) = v;
        }
        #pragma unroll
        for (int i = 0; i < WIT; i++){
            int idx = tid * 8 + i * 2048;
            int r = idx / BK, c = idx % BK;
            *(ushort8v*)(Ws + r * BKp + c) = wr[i];
        }
        __syncthreads();
        if (k0 + BK < K) load_tile(k0 + BK);      // prefetch overlaps MFMA phase
        #pragma unroll
        for (int ks = 0; ks < BK; ks += 32){
            bf16x8 af[FM], bfr[FN];
            #pragma unroll
            for (int i = 0; i < FM; i++){
                const unsigned short* p = As + (wm + i * 16 + row16) * BKp + ks + q * 8;
                af[i] = __builtin_bit_cast(bf16x8, *(const short8*)p);
            }
            #pragma unroll
            for (int j = 0; j < FN; j++){
                const unsigned short* p = Ws + (wn + j * 16 + row16) * BKp + ks + q * 8;
                bfr[j] = __builtin_bit_cast(bf16x8, *(const short8*)p);
            }
            #pragma unroll
            for (int i = 0; i < FM; i++)
                #pragma unroll
                for (int j = 0; j < FN; j++)
                    acc[i][j] = __builtin_amdgcn_mfma_f32_16x16x32_bf16(af[i], bfr[j], acc[i][j], 0, 0, 0);
        }
        __syncthreads();
    }
    #pragma unroll
    for (int j = 0; j < FN; j++){
        int n = n0 + wn + j * 16 + row16;
        float bv = (EPI == 1) ? bias[n] : 0.f;
        #pragma unroll
        for (int i = 0; i < FM; i++){
            #pragma unroll
            for (int r = 0; r < 4; r++){
                int m = m0 + wm + i * 16 + q * 4 + r;
                float v = acc[i][j][r];
                if (EPI == 1) v = softplus_f(v + bv);
                if constexpr (OUTBF)
                    ((unsigned short*)Cout)[(size_t)m * ldc + n] = f2bf(v);
                else
                    ((float*)Cout)[(size_t)m * ldc + n] = v;
            }
        }
    }
}

template<int BM,int BN,int BK,int NWM,int NWN,int OUTBF,int EPI>
__global__ __launch_bounds__(256) void gemm_bf(
    const unsigned short* __restrict__ A, const unsigned short* __restrict__ W,
    const float* __restrict__ bias, void* Cout, int K, int lda, int ldw, int ldc)
{
    gemm_bf_body<BM,BN,BK,NWM,NWN,OUTBF,EPI,false>(A, nullptr, W, bias, Cout, K, lda, ldw, ldc);
}

// dual-direction (blockIdx.z picks fw/bw)
template<int BM,int BN,int BK,int NWM,int NWN,int OUTBF,int EPI>
__global__ __launch_bounds__(256) void gemm_bf_dual(
    const unsigned short* __restrict__ Af, const unsigned short* __restrict__ Ab,
    const unsigned short* __restrict__ Wf, const unsigned short* __restrict__ Wb,
    void* Cf, void* Cb, int K, int lda, int ldw, int ldc)
{
    const int d = blockIdx.z;
    gemm_bf_body<BM,BN,BK,NWM,NWN,OUTBF,EPI,false>(d ? Ab : Af, nullptr, d ? Wb : Wf,
                                                   nullptr, d ? Cb : Cf, K, lda, ldw, ldc);
}

// out_proj: A = bf16(Ya)+bf16(Yb), fp32 C
__global__ __launch_bounds__(256) void gemm_ybf(
    const unsigned short* __restrict__ Ya, const unsigned short* __restrict__ Yb,
    const unsigned short* __restrict__ W, float* __restrict__ C)
{
    gemm_bf_body<64,64,64,2,2,0,0,true>(Ya, Yb, W, nullptr, C, DINNER, DINNER, DINNER, DMODEL);
}

// ---------- dt-proj: delta = softplus(xdbl[:, :32] @ dt_w^T + dt_b), K=32 single tile ----------
__global__ __launch_bounds__(256) void gemm_dt_dual(
    const float* __restrict__ xdf, const float* __restrict__ xdb,
    const unsigned short* __restrict__ wdf, const unsigned short* __restrict__ wdb,
    const float* __restrict__ bf_, const float* __restrict__ bb_,
    unsigned short* __restrict__ df, unsigned short* __restrict__ db)
{
    constexpr int BM = 128, BN = 128, BKp = 40;   // K=32, pitch 40 shorts (80 B)
    const int d = blockIdx.z;
    const float* __restrict__ xd = d ? xdb : xdf;
    const unsigned short* __restrict__ wd = d ? wdb : wdf;
    const float* __restrict__ bias = d ? bb_ : bf_;
    unsigned short* __restrict__ delta = d ? db : df;
    __shared__ unsigned short As[BM * BKp];
    __shared__ unsigned short Ws[BN * BKp];
    const int tid  = threadIdx.x;
    const int wave = tid >> 6, lane = tid & 63;
    const int row16 = lane & 15, q = lane >> 4;
    const int wm = (wave >> 1) * 64;
    const int wn = (wave & 1) * 64;
    const int m0 = blockIdx.y * BM;
    const int n0 = blockIdx.x * BN;

    #pragma unroll
    for (int i = 0; i < 4; i++){                  // A: 128x32 fp32 -> bf16
        int idx = tid + i * 256;                  // float4 slots
        int r = idx >> 3, cq = (idx & 7) * 4;
        float4 v = *(const float4*)(xd + (size_t)(m0 + r) * 64 + cq);
        ushort4v s = { f2bf(v.x), f2bf(v.y), f2bf(v.z), f2bf(v.w) };
        *(ushort4v*)(As + r * BKp + cq) = s;
    }
    #pragma unroll
    for (int i = 0; i < 2; i++){                  // W: 128x32 bf16
        int idx = tid + i * 256;                  // ushort8 slots
        int r = idx >> 2, c8 = (idx & 3) * 8;
        *(ushort8v*)(Ws + r * BKp + c8) = *(const ushort8v*)(wd + (size_t)(n0 + r) * 32 + c8);
    }
    __syncthreads();
    f32x4 acc[4][4] = {};
    bf16x8 af[4], bfr[4];
    #pragma unroll
    for (int i = 0; i < 4; i++)
        af[i] = __builtin_bit_cast(bf16x8, *(const short8*)(As + (wm + i * 16 + row16) * BKp + q * 8));
    #pragma unroll
    for (int j = 0; j < 4; j++)
        bfr[j] = __builtin_bit_cast(bf16x8, *(const short8*)(Ws + (wn + j * 16 + row16) * BKp + q * 8));
    #pragma unroll
    for (int i = 0; i < 4; i++)
        #pragma unroll
        for (int j = 0; j < 4; j++)
            acc[i][j] = __builtin_amdgcn_mfma_f32_16x16x32_bf16(af[i], bfr[j], acc[i][j], 0, 0, 0);
    #pragma unroll
    for (int j = 0; j < 4; j++){
        int n = n0 + wn + j * 16 + row16;
        float bv = bias[n];
        #pragma unroll
        for (int i = 0; i < 4; i++)
            #pragma unroll
            for (int r = 0; r < 4; r++){
                int m = m0 + wm + i * 16 + q * 4 + r;
                delta[(size_t)m * DINNER + n] = f2bf(softplus_f(acc[i][j][r] + bv));
            }
    }
}

// ---------- depthwise causal conv(K=4) + SiLU, bf16 in/out ----------
__global__ __launch_bounds__(256) void conv_silu_bf(
    const unsigned short* __restrict__ uxb,
    const float* __restrict__ w_f, const float* __restrict__ b_f,
    const float* __restrict__ w_b, const float* __restrict__ b_b,
    unsigned short* __restrict__ uc_f, unsigned short* __restrict__ uc_b)
{
    const int dir = blockIdx.y;
    const float* __restrict__ w    = dir ? w_b : w_f;
    const float* __restrict__ bias = dir ? b_b : b_f;
    unsigned short* __restrict__ uc = dir ? uc_b : uc_f;
    int idx = blockIdx.x * 256 + threadIdx.x;     // ushort8 slot
    int e = idx * 8;
    int dq = e & (DINNER - 1);
    int t  = (e >> 10) & (LSEQ - 1);
    int b  = e >> 21;
    float wk[32];
    const float* wp = w + dq * 4;
    #pragma unroll
    for (int i = 0; i < 32; i++) wk[i] = wp[i];
    float acc[8];
    #pragma unroll
    for (int i = 0; i < 8; i++) acc[i] = bias[dq + i];
    #pragma unroll
    for (int k = 0; k < 4; k++){
        int src = t + k - 3;
        if (src >= 0){
            int gt = dir ? (LSEQ - 1 - src) : src;
            ushort8v uv = *(const ushort8v*)(uxb + ((size_t)b * LSEQ + gt) * 2048 + dq);
            #pragma unroll
            for (int i = 0; i < 8; i++) acc[i] = fmaf(wk[i * 4 + k], bf2f(uv[i]), acc[i]);
        }
    }
    ushort8v o;
    #pragma unroll
    for (int i = 0; i < 8; i++) o[i] = f2bf(silu_f(acc[i]));
    *(ushort8v*)(uc + ((size_t)b * LSEQ + t) * DINNER + dq) = o;
}

// ================= register-state chunked scan (bf16 delta/u/z) =================
__global__ __launch_bounds__(256) void scan_pass1(
    const unsigned short* __restrict__ delta_f, const unsigned short* __restrict__ delta_b,
    const unsigned short* __restrict__ uc_f,    const unsigned short* __restrict__ uc_b,
    const float* __restrict__ xdbl_f,  const float* __restrict__ xdbl_b,
    const float* __restrict__ Alog_f,  const float* __restrict__ Alog_b,
    float* __restrict__ hseg, float* __restrict__ dsum)
{
    const int wave = threadIdx.x >> 6, lane = threadIdx.x & 63;
    const int unit = blockIdx.x * 4 + wave;
    const int cw = unit >> 5;
    const int s  = unit & 31;
    const int chd0 = cw << 6;
    const int dir = chd0 >> 11;
    const int b   = (chd0 >> 10) & 1;
    const int d0  = chd0 & 1023;
    const int c   = d0 + lane;
    const unsigned short* __restrict__ delta = dir ? delta_b : delta_f;
    const unsigned short* __restrict__ uc    = dir ? uc_b    : uc_f;
    const float* __restrict__ xdbl  = dir ? xdbl_b  : xdbl_f;
    const float* __restrict__ Alog  = dir ? Alog_b  : Alog_f;
    const float L2E = 1.4426950408889634f;

    float a2[16];
    {
        const float4* ap = (const float4*)(Alog + c * 16);
        float4 t0 = ap[0], t1 = ap[1], t2 = ap[2], t3 = ap[3];
        float tmp[16];
        *(float4*)(tmp+0)=t0; *(float4*)(tmp+4)=t1; *(float4*)(tmp+8)=t2; *(float4*)(tmp+12)=t3;
        #pragma unroll
        for (int n = 0; n < 16; n++) a2[n] = -fast_exp2(tmp[n] * L2E) * L2E;
    }
    float h[16];
    #pragma unroll
    for (int n = 0; n < 16; n++) h[n] = 0.f;
    float dacc = 0.f;
    const size_t rb = (size_t)b * LSEQ;
    const int tb = s * TSEG, te = tb + TSEG;

    size_t m = rb + tb;
    float dl = bf2f(delta[m * DINNER + c]);
    float uv = bf2f(uc[m * DINNER + c]);
    float4 B0, B1, B2, B3;
    { const float4* xb = (const float4*)(xdbl + m * 64 + 32); B0=xb[0]; B1=xb[1]; B2=xb[2]; B3=xb[3]; }

    for (int t = tb; t < te; t++){
        int tn = (t + 1 < te) ? t + 1 : t;
        size_t mn = rb + tn;
        float dl_n = bf2f(delta[mn * DINNER + c]);
        float uv_n = bf2f(uc[mn * DINNER + c]);
        float4 Bn0, Bn1, Bn2, Bn3;
        { const float4* xb = (const float4*)(xdbl + mn * 64 + 32); Bn0=xb[0]; Bn1=xb[1]; Bn2=xb[2]; Bn3=xb[3]; }
        float Ba[16];
        *(float4*)(Ba+0)=B0; *(float4*)(Ba+4)=B1; *(float4*)(Ba+8)=B2; *(float4*)(Ba+12)=B3;
        float du = dl * uv;
        dacc += dl;
        #pragma unroll
        for (int n = 0; n < 16; n++)
            h[n] = fmaf(fast_exp2(dl * a2[n]), h[n], du * Ba[n]);
        dl = dl_n; uv = uv_n; B0=Bn0; B1=Bn1; B2=Bn2; B3=Bn3;
    }
    float* hp = hseg + ((size_t)(chd0 + lane) * SSEG + s) * 16;
    *(float4*)(hp+0)  = (float4){h[0],h[1],h[2],h[3]};
    *(float4*)(hp+4)  = (float4){h[4],h[5],h[6],h[7]};
    *(float4*)(hp+8)  = (float4){h[8],h[9],h[10],h[11]};
    *(float4*)(hp+12) = (float4){h[12],h[13],h[14],h[15]};
    dsum[s * 4096 + chd0 + lane] = dacc;
}

__global__ __launch_bounds__(256) void scan_combine(
    const float* __restrict__ dsum,
    const float* __restrict__ Alog_f, const float* __restrict__ Alog_b,
    float* __restrict__ hseg)
{
    int idx = blockIdx.x * 256 + threadIdx.x;
    int n   = idx & 15;
    int chd = idx >> 4;
    int dir = chd >> 11;
    int d   = chd & 1023;
    const float* __restrict__ Alog = dir ? Alog_b : Alog_f;
    const float L2E = 1.4426950408889634f;
    const float A2 = -fast_exp2(Alog[d * NSTATE + n] * L2E) * L2E;
    float H = 0.f;
    #pragma unroll
    for (int s = 0; s < SSEG; s++){
        size_t base = ((size_t)chd * SSEG + s) * 16 + n;
        float hv = hseg[base];
        float ds = dsum[s * 4096 + chd];
        hseg[base] = H;
        H = fmaf(fast_exp2(A2 * ds), H, hv);
    }
}

__global__ __launch_bounds__(256) void scan_pass2(
    const unsigned short* __restrict__ delta_f, const unsigned short* __restrict__ delta_b,
    const unsigned short* __restrict__ uc_f,    const unsigned short* __restrict__ uc_b,
    const float* __restrict__ xdbl_f,  const float* __restrict__ xdbl_b,
    const unsigned short* __restrict__ uxb,
    const float* __restrict__ Alog_f,  const float* __restrict__ Alog_b,
    const float* __restrict__ Dv_f,    const float* __restrict__ Dv_b,
    const float* __restrict__ hseg,
    unsigned short* __restrict__ ybuf_f, unsigned short* __restrict__ ybuf_b)
{
    const int wave = threadIdx.x >> 6, lane = threadIdx.x & 63;
    const int unit = blockIdx.x * 4 + wave;
    const int cw = unit >> 5;
    const int s  = unit & 31;
    const int chd0 = cw << 6;
    const int dir = chd0 >> 11;
    const int b   = (chd0 >> 10) & 1;
    const int d0  = chd0 & 1023;
    const int c   = d0 + lane;
    const unsigned short* __restrict__ delta = dir ? delta_b : delta_f;
    const unsigned short* __restrict__ uc    = dir ? uc_b    : uc_f;
    const float* __restrict__ xdbl  = dir ? xdbl_b  : xdbl_f;
    const float* __restrict__ Alog  = dir ? Alog_b  : Alog_f;
    const float* __restrict__ Dv    = dir ? Dv_b    : Dv_f;
    unsigned short* __restrict__ ybuf = dir ? ybuf_b : ybuf_f;
    const float L2E = 1.4426950408889634f;

    float a2[16];
    {
        const float4* ap = (const float4*)(Alog + c * 16);
        float4 t0 = ap[0], t1 = ap[1], t2 = ap[2], t3 = ap[3];
        float tmp[16];
        *(float4*)(tmp+0)=t0; *(float4*)(tmp+4)=t1; *(float4*)(tmp+8)=t2; *(float4*)(tmp+12)=t3;
        #pragma unroll
        for (int n = 0; n < 16; n++) a2[n] = -fast_exp2(tmp[n] * L2E) * L2E;
    }
    const float Dval = Dv[c];
    float h[16];
    {
        const float* hp = hseg + ((size_t)(chd0 + lane) * SSEG + s) * 16;
        float4 h0 = *(const float4*)(hp+0), h1 = *(const float4*)(hp+4);
        float4 h2 = *(const float4*)(hp+8), h3 = *(const float4*)(hp+12);
        *(float4*)(h+0)=h0; *(float4*)(h+4)=h1; *(float4*)(h+8)=h2; *(float4*)(h+12)=h3;
    }
    const size_t rb = (size_t)b * LSEQ;
    const int tb = s * TSEG, te = tb + TSEG;

    size_t m = rb + tb;
    int ot0 = dir ? (LSEQ - 1 - tb) : tb;
    float dl = bf2f(delta[m * DINNER + c]);
    float uv = bf2f(uc[m * DINNER + c]);
    float zv = bf2f(uxb[(rb + ot0) * 2048 + 1024 + c]);
    float4 B0,B1,B2,B3, C0,C1,C2,C3;
    { const float4* xb = (const float4*)(xdbl + m * 64 + 32);
      B0=xb[0]; B1=xb[1]; B2=xb[2]; B3=xb[3];
      C0=xb[4]; C1=xb[5]; C2=xb[6]; C3=xb[7]; }

    for (int t = tb; t < te; t++){
        int tn = (t + 1 < te) ? t + 1 : t;
        size_t mn = rb + tn;
        int otn = dir ? (LSEQ - 1 - tn) : tn;
        float dl_n = bf2f(delta[mn * DINNER + c]);
        float uv_n = bf2f(uc[mn * DINNER + c]);
        float zv_n = bf2f(uxb[(rb + otn) * 2048 + 1024 + c]);
        float4 Bn0,Bn1,Bn2,Bn3, Cn0,Cn1,Cn2,Cn3;
        { const float4* xb = (const float4*)(xdbl + mn * 64 + 32);
          Bn0=xb[0]; Bn1=xb[1]; Bn2=xb[2]; Bn3=xb[3];
          Cn0=xb[4]; Cn1=xb[5]; Cn2=xb[6]; Cn3=xb[7]; }

        float Ba[16], Ca[16];
        *(float4*)(Ba+0)=B0; *(float4*)(Ba+4)=B1; *(float4*)(Ba+8)=B2; *(float4*)(Ba+12)=B3;
        *(float4*)(Ca+0)=C0; *(float4*)(Ca+4)=C1; *(float4*)(Ca+8)=C2; *(float4*)(Ca+12)=C3;
        float du = dl * uv;
        float y = uv * Dval;
        #pragma unroll
        for (int n = 0; n < 16; n++){
            h[n] = fmaf(fast_exp2(dl * a2[n]), h[n], du * Ba[n]);
            y = fmaf(h[n], Ca[n], y);
        }
        y *= silu_f(zv);
        int ot = dir ? (LSEQ - 1 - t) : t;
        ybuf[(rb + ot) * DINNER + c] = f2bf(y);

        dl = dl_n; uv = uv_n; zv = zv_n;
        B0=Bn0; B1=Bn1; B2=Bn2; B3=Bn3;
        C0=Cn0; C1=Cn1; C2=Cn2; C3=Cn3;
    }
}

// ---------- host launch ----------
extern "C" void kernel_launch(void* const* d_in, const int* in_sizes, int n_in,
                              void* d_out, int out_size, void* d_ws, size_t ws_size,
                              hipStream_t stream)
{
    const float* x         = (const float*)d_in[0];
    const float* ln1_w     = (const float*)d_in[1];
    const float* ln1_b     = (const float*)d_in[2];
    const float* ln2_w     = (const float*)d_in[3];
    const float* ln2_b     = (const float*)d_in[4];
    const float* in_proj_w = (const float*)d_in[5];
    const float* conv_w_f  = (const float*)d_in[6];
    const float* conv_b_f  = (const float*)d_in[7];
    const float* xproj_f   = (const float*)d_in[8];
    const float* dt_w_f    = (const float*)d_in[9];
    const float* dt_b_f    = (const float*)d_in[10];
    const float* Alog_f    = (const float*)d_in[11];
    const float* D_f       = (const float*)d_in[12];
    const float* conv_w_b  = (const float*)d_in[13];
    const float* conv_b_b  = (const float*)d_in[14];
    const float* xproj_b   = (const float*)d_in[15];
    const float* dt_w_b    = (const float*)d_in[16];
    const float* dt_b_b    = (const float*)d_in[17];
    const float* Alog_b    = (const float*)d_in[18];
    const float* D_b       = (const float*)d_in[19];
    const float* outproj   = (const float*)d_in[20];
    float* out = (float*)d_out;

    // ---- workspace layout ----
    float* ws      = (float*)d_ws;
    float* out_pre = ws;                            // 2,097,152 f
    float* hseg    = ws + 2097152;                  // 2,097,152 f
    float* dsum    = ws + 4194304;                  //   131,072 f
    float* xdbl_f  = ws + 4325376;                  //   262,144 f
    float* xdbl_b  = ws + 4587520;                  //   262,144 f
    unsigned short* us = (unsigned short*)(ws + 4849664);
    unsigned short* xn      = us;                   // 2,097,152
    unsigned short* uxb     = us + 2097152;         // 8,388,608
    unsigned short* uc_f    = us + 10485760;        // 4,194,304
    unsigned short* uc_b    = us + 14680064;        // 4,194,304
    unsigned short* delta_f = us + 18874368;        // 4,194,304
    unsigned short* delta_b = us + 23068672;        // 4,194,304
    unsigned short* ybuf_f  = us + 27262976;        // 4,194,304
    unsigned short* ybuf_b  = us + 31457280;        // 4,194,304
    unsigned short* wpin    = us + 35651584;        // 1,048,576
    unsigned short* wpout   = us + 36700160;        //   524,288
    unsigned short* wxp_f   = us + 37224448;        //    65,536
    unsigned short* wxp_b   = us + 37289984;        //    65,536
    unsigned short* wdt_f   = us + 37355520;        //    32,768
    unsigned short* wdt_b   = us + 37388288;        //    32,768

    // 0. weights -> bf16 (1,769,472 elems / 4 / 256 = 1728 blocks)
    convert_weights<<<1728, 256, 0, stream>>>(
        in_proj_w, outproj, xproj_f, xproj_b, dt_w_f, dt_w_b,
        wpin, wpout, wxp_f, wxp_b, wdt_f, wdt_b);
    // 1. LN1 -> bf16 xn
    ln_bf_kernel<<<MROWS, 256, 0, stream>>>(x, ln1_w, ln1_b, xn);
    // 2. in_proj: ux[4096,2048](bf16) = xn @ in_proj_w^T
    gemm_bf<128,128,64,2,2,1,0><<<dim3(16,32), 256, 0, stream>>>(
        xn, wpin, nullptr, uxb, 512, 512, 512, 2048);
    // 3. causal conv + silu -> bf16 uc
    conv_silu_bf<<<dim3(2048,2), 256, 0, stream>>>(
        uxb, conv_w_f, conv_b_f, conv_w_b, conv_b_b, uc_f, uc_b);
    // 4. x_proj fw+bw: xdbl[4096,64](fp32) = uc @ x_proj_w^T
    gemm_bf_dual<64,64,64,2,2,0,0><<<dim3(1,64,2), 256, 0, stream>>>(
        uc_f, uc_b, wxp_f, wxp_b, xdbl_f, xdbl_b, 1024, 1024, 1024, 64);
    // 5. delta(bf16) = softplus(xdbl[:, :32] @ dt_w^T + dt_b)
    gemm_dt_dual<<<dim3(8,32,2), 256, 0, stream>>>(
        xdbl_f, xdbl_b, wdt_f, wdt_b, dt_b_f, dt_b_b, delta_f, delta_b);
    // 6. chunked selective scan
    scan_pass1<<<512, 256, 0, stream>>>(
        delta_f, delta_b, uc_f, uc_b, xdbl_f, xdbl_b, Alog_f, Alog_b, hseg, dsum);
    scan_combine<<<256, 256, 0, stream>>>(dsum, Alog_f, Alog_b, hseg);
    scan_pass2<<<512, 256, 0, stream>>>(
        delta_f, delta_b, uc_f, uc_b, xdbl_f, xdbl_b, uxb,
        Alog_f, Alog_b, D_f, D_b, hseg, ybuf_f, ybuf_b);
    // 7. out_proj: out_pre(fp32) = (ybuf_f + ybuf_b) @ out_proj_w^T
    gemm_ybf<<<dim3(8,64), 256, 0, stream>>>(ybuf_f, ybuf_b, wpout, out_pre);
    // 8. LN2(out_pre + x) -> d_out
    ln_kernel<<<MROWS, 256, 0, stream>>>(out_pre, x, ln2_w, ln2_b, out);
}